// Round 24
// baseline (120.862 us; speedup 1.0000x reference)
//
#include <hip/hip_runtime.h>
#include <hip/hip_bf16.h>
#include <math.h>

// MultiHeadAttention: B=2, S=2048, D=1024, H=16, HD=64
// Pipeline: fused cvt (+mask->w tables) | QKV GEMM (MFMA bf16, 2-phase dbuf) |
// flash attn.
// Attn (r23 body + kv-split x2): 512 blocks x 512 thr (8 waves). Waves 0-3
// sweep kv[0,1024), waves 4-7 kv[1024,2048); each wave owns 32 q-rows
// (2 subtiles). Swapped-QK, P^T in registers. Per-half K dbuf via
// global_load_lds (one __syncthreads/iter). V'/w register-prefetched one tile
// ahead (r23). QK C-in = 0. Denominator via w-fragment MFMA. Fixed-shift-free
// exp2 softmax -> kv combine is a PURE fp32 SUM (exact, deterministic):
// half-1 publishes of via transposed [32][256] LDS (bank=lane%32, no
// conflicts) union'd over dead K bufs + 512B of_l corner; half-0 adds+writes.
// Rationale: 32 rows/wave => only 2 waves/SIMD from the q-dimension; kv-split
// doubles to 4/SIMD to hide the QK->exp->PV chain (r15 retry on lean body).

typedef __bf16 bf16_t;
typedef __attribute__((ext_vector_type(8))) __bf16 bf16x8;
typedef __attribute__((ext_vector_type(4))) __bf16 bf16x4;
typedef __attribute__((ext_vector_type(4))) float f32x4;

#define B_  2
#define S_  2048
#define D_  1024
#define H_  16
#define HD_ 64
#define M_  (B_ * S_)   // 4096
#define K_  D_          // 1024
#define NT_ (S_ / 64)   // 32 kv tiles
#define NTH_ (NT_ / 2)  // 16 tiles per half
#define LOG2E 1.44269504f
#define CS_Q (0.125f * LOG2E)   // folded into Q at GEMM epilogue

#if __has_builtin(__builtin_amdgcn_exp2f)
#define EXP2F(x) __builtin_amdgcn_exp2f(x)
#else
#define EXP2F(x) exp2f(x)
#endif

__device__ __forceinline__ f32x4 mfma16x16x32(bf16x8 a, bf16x8 b, f32x4 c) {
    return __builtin_amdgcn_mfma_f32_16x16x32_bf16(a, b, c, 0, 0, 0);
}

__device__ __forceinline__ void gload_lds16(const bf16_t* g, bf16_t* l) {
    __builtin_amdgcn_global_load_lds(
        (const __attribute__((address_space(1))) void*)g,
        (__attribute__((address_space(3))) void*)l,
        16, 0, 0);
}

// ---------------------------------------------------------------- conversion
// Segments: X (1,048,576 f4) | Wq | Wk | Wv (262,144 f4 each) | mask (1024 f4).
// Mask -> w = e^mask: f32 table wfp[B][S] (folded into V at GEMM epilogue)
// and bf16 B-fragment table wfb[B][32 t][4 kg][16 e] (denominator MFMA).
__global__ void cvt_all(const float* __restrict__ hs, const float* __restrict__ wq,
                        const float* __restrict__ wk, const float* __restrict__ wv,
                        const float* __restrict__ mask,
                        bf16_t* __restrict__ Xb, bf16_t* __restrict__ Wb3,
                        float* __restrict__ wfp, bf16_t* __restrict__ wfb) {
    const int i = blockIdx.x * blockDim.x + threadIdx.x;
    if (i >= 1835008) {                     // mask segment (block-aligned tail)
        const int off = i - 1835008;
        if (off < 1024) {
            float4 v = ((const float4*)mask)[off];
            float4 w4;
            w4.x = exp2f(v.x * LOG2E); w4.y = exp2f(v.y * LOG2E);
            w4.z = exp2f(v.z * LOG2E); w4.w = exp2f(v.w * LOG2E);
            ((float4*)wfp)[off] = w4;
            // bf16 fragment table: k = t*64 + nb*16 + kg*4 + j, e = nb*4 + j
            const int k4 = off * 4;
            const int bb = k4 >> 11, k = k4 & 2047;
            const int t  = k >> 6,  kt = k & 63;
            const int nb = kt >> 4, kgf = (kt >> 2) & 3;   // j = 0..3
            bf16x4 wb4;
            wb4[0] = (bf16_t)w4.x; wb4[1] = (bf16_t)w4.y;
            wb4[2] = (bf16_t)w4.z; wb4[3] = (bf16_t)w4.w;
            *(bf16x4*)&wfb[(((size_t)bb * 32 + t) * 4 + kgf) * 16 + nb * 4] = wb4;
        }
        return;
    }
    const float* src; bf16_t* dst; int off;
    if (i < 1048576)      { src = hs; dst = Xb;            off = i; }
    else if (i < 1310720) { src = wq; dst = Wb3;           off = i - 1048576; }
    else if (i < 1572864) { src = wk; dst = Wb3 + 1048576; off = i - 1310720; }
    else                  { src = wv; dst = Wb3 + 2097152; off = i - 1572864; }
    float4 v = ((const float4*)src)[off];
    bf16x4 o;
    o[0] = (bf16_t)v.x; o[1] = (bf16_t)v.y;
    o[2] = (bf16_t)v.z; o[3] = (bf16_t)v.w;
    ((bf16x4*)dst)[off] = o;
}

// ---------------------------------------------------------------- QKV GEMM
// z=0 -> Q [B][H][S][HD], PRE-SCALED by CS_Q (0.125*log2e)
// z=1 -> K [B][H][S][HD]
// z=2 -> V' in MFMA-B-fragment order, W-FOLDED: V'[k][d] = (V[k][d])*w[b][k].
//        Vfrag[bh][t][db][lane=kg*16+lq][e=nb*4+j], k = t*64+nb*16+kg*4+j,
//        d = db*16+lq.
// 2-phase LDS double-buffer: stage(k+1) issued before compute(k), one barrier.
__global__ __launch_bounds__(256, 2)
void gemm_qkv(const bf16_t* __restrict__ Xb, const bf16_t* __restrict__ Wb3,
              const float* __restrict__ bq, const float* __restrict__ bk,
              const float* __restrict__ bv,
              const float* __restrict__ wfp,
              bf16_t* __restrict__ Qo, bf16_t* __restrict__ Ko,
              bf16_t* __restrict__ Vf) {
    __shared__ bf16_t smem[2][8192];        // dbuf: A 128x32 | B 128x32 per buf
    const int z = blockIdx.z;
    const bf16_t* Wb = Wb3 + (size_t)z * (D_ * K_);
    const float* bias = (z == 0) ? bq : (z == 1) ? bk : bv;

    const int tid  = threadIdx.x;
    const int lane = tid & 63;
    const int w    = tid >> 6;
    const int wr   = w >> 1, wc = w & 1;
    const int m0   = blockIdx.y * 128;
    const int n0   = blockIdx.x * 128;

    f32x4 acc[4][4];
    const f32x4 fzero = {0.f, 0.f, 0.f, 0.f};
#pragma unroll
    for (int i = 0; i < 4; i++)
#pragma unroll
        for (int j = 0; j < 4; j++) acc[i][j] = fzero;

    const int koff = (lane >> 4) * 8;

    auto stage = [&](int k0, int buf) {
#pragma unroll
        for (int i = 0; i < 4; i++) {
            const int chunk  = w * 4 + i;
            const int byteoff = chunk * 1024 + lane * 16;
            bf16_t* ldst = &smem[buf][chunk * 512];     // wave-uniform base
            const bf16_t* gsrc;
            if (byteoff < 8192) {                        // A region
                int row = byteoff >> 6;
                int col = (byteoff & 63) >> 1;
                gsrc = Xb + (size_t)(m0 + row) * K_ + k0 + col;
            } else {                                     // B region
                int bo  = byteoff - 8192;
                int row = bo >> 6;
                int col = (bo & 63) >> 1;
                gsrc = Wb + (size_t)(n0 + row) * K_ + k0 + col;
            }
            gload_lds16(gsrc, ldst);
        }
    };

    stage(0, 0);
    __syncthreads();

    for (int kk = 0; kk < K_ / 32; ++kk) {
        const int cur = kk & 1;
        if (kk + 1 < K_ / 32) stage((kk + 1) * 32, cur ^ 1);  // overlaps below

        bf16x8 af[4], bfr[4];
#pragma unroll
        for (int m = 0; m < 4; m++) {
            int row = wr * 64 + m * 16 + (lane & 15);
            af[m] = *(const bf16x8*)&smem[cur][row * 32 + koff];
        }
#pragma unroll
        for (int n = 0; n < 4; n++) {
            int row = wc * 64 + n * 16 + (lane & 15);
            bfr[n] = *(const bf16x8*)&smem[cur][4096 + row * 32 + koff];
        }
#pragma unroll
        for (int m = 0; m < 4; m++)
#pragma unroll
            for (int n = 0; n < 4; n++)
                acc[m][n] = mfma16x16x32(af[m], bfr[n], acc[m][n]);

        // one barrier/iter: publishes stage(kk+1) AND guards buf reuse
        __syncthreads();
    }

#pragma unroll
    for (int m = 0; m < 4; m++) {
        const int gm    = m0 + wr * 64 + m * 16 + ((lane >> 4) << 2);
        const int bidx  = gm >> 11;
        const int sbase = gm & 2047;                    // multiple of 4
#pragma unroll
        for (int n = 0; n < 4; n++) {
            const int gn = n0 + wc * 64 + n * 16 + (lane & 15);
            const int h  = gn >> 6, hd = gn & 63;
            const float bias_v = bias[gn];
            const size_t bh = (size_t)bidx * H_ + h;
            if (z == 2) {
                // fragment-order, w-folded V write: one 8B store
                const int t   = sbase >> 6, k0i = sbase & 63;
                const int nb  = k0i >> 4, kgf = (k0i >> 2) & 3;
                const int db  = hd >> 4,  lqf = hd & 15;
                const float4 w4 = *(const float4*)&wfp[bidx * S_ + sbase];
                bf16x4 pack;
                pack[0] = (bf16_t)((acc[m][n][0] + bias_v) * w4.x);
                pack[1] = (bf16_t)((acc[m][n][1] + bias_v) * w4.y);
                pack[2] = (bf16_t)((acc[m][n][2] + bias_v) * w4.z);
                pack[3] = (bf16_t)((acc[m][n][3] + bias_v) * w4.w);
                bf16_t* dst = Vf + ((bh * 32 + t) * 4 + db) * 1024 +
                    (kgf * 16 + lqf) * 16 + nb * 4;
                *(bf16x4*)dst = pack;
            } else if (z == 0) {
#pragma unroll
                for (int j = 0; j < 4; j++) {
                    float y = (acc[m][n][j] + bias_v) * CS_Q;
                    Qo[(bh * S_ + sbase + j) * HD_ + hd] = (bf16_t)y;
                }
            } else {
#pragma unroll
                for (int j = 0; j < 4; j++) {
                    float y = acc[m][n][j] + bias_v;
                    Ko[(bh * S_ + sbase + j) * HD_ + hd] = (bf16_t)y;
                }
            }
        }
    }
}

// ---------------------------------------------------------------- attention
// Grid 512 (16 qtiles x 32 heads), XCD-aware. 8 waves: wq = w&3 (q-subtile),
// half = w>>2 (kv half). LDS 33.25K: 4 x K 8K (2 per half) + 512B of_l corner;
// after the loop the K region is reused as the [32][256] of-exchange.
__global__ __launch_bounds__(512, 4)
void attn_fwd(const bf16_t* __restrict__ Qb, const bf16_t* __restrict__ Kb,
              const bf16_t* __restrict__ Vf, const bf16_t* __restrict__ Wfb,
              float* __restrict__ out) {
    const int flat = blockIdx.x;
    const int xcd  = flat & 7;
    const int idx  = flat >> 3;            // 0..63
    const int bh   = xcd * 4 + (idx >> 4); // 0..31
    const int qt   = idx & 15;             // 0..15 (128-row tiles)
    const int b    = bh >> 4;
    const int h    = bh & 15;

    const int tid  = threadIdx.x, lane = tid & 63, w = tid >> 6;
    const int wq   = w & 3;
    const int half = w >> 2;

    const bf16_t* Qh = Qb + (size_t)bh * S_ * HD_;
    const bf16_t* Kh = Kb + (size_t)bh * S_ * HD_;
    const bf16_t* Vh = Vf + (size_t)bh * 32 * 4096;   // [t][db][lane][16]
    const bf16_t* Wh = Wfb + (size_t)b * 32 * 64;     // [t][kg][16]

    __shared__ char ShBuf[33280];          // 4 x K 8K | union of-exch; +512B l
    float* exf = (float*)ShBuf;            // [32][256] after loop
    float* exl = (float*)(ShBuf + 32768);  // [128] of_l corner

    const int lq   = lane & 15;
    const int kg   = lane >> 4;            // 0..3
    const int koff = kg * 8;
    const int rsub = lane >> 3;            // staging: row-in-chunk 0..7
    const int csl8 = (lane & 7) * 8;       // staging: 16B slot -> elements

    // per-half K stage (8 KB by this half's 4 waves, 2 chunks/wave)
    auto stageK = [&](int kv0, int buf) {
        bf16_t* base = (bf16_t*)(ShBuf + (half * 2 + buf) * 8192);
#pragma unroll
        for (int i = 0; i < 2; i++) {
            const int c = wq * 2 + i;                   // 0..7, wave-uniform
            bf16_t* ldst = base + c * 512;              // 1 KB chunks
            const int cel = csl8 ^ (rsub * 8);          // pre-swizzled source col
            const bf16_t* gsrc = Kh + (size_t)(kv0 + c * 8 + rsub) * HD_ + cel;
            gload_lds16(gsrc, ldst);
        }
    };

    // ---- Q fragments: 2 subtiles of 16 rows (32 rows/wave, block tile 128)
    const int qbase = qt * 128 + wq * 32;
    bf16x8 qf0[2], qf1[2];
#pragma unroll
    for (int s = 0; s < 2; s++) {
        const bf16_t* qr = Qh + (size_t)(qbase + s * 16 + lq) * HD_;
        qf0[s] = *(const bf16x8*)(qr + koff);
        qf1[s] = *(const bf16x8*)(qr + 32 + koff);
    }

    const f32x4 fzero = {0.f, 0.f, 0.f, 0.f};
    f32x4 of[2][4];
    f32x4 of_l[2];                          // denominator accumulators
#pragma unroll
    for (int s = 0; s < 2; s++) {
        of_l[s] = fzero;
#pragma unroll
        for (int i = 0; i < 4; i++) of[s][i] = fzero;
    }

    const int rdsw = (lq & 7) << 4;        // K read swizzle: (row&7)<<4 bytes
    const int t0 = half * NTH_;

    // ---- prologue: V(t0)/w(t0) into registers; K(t0) into LDS
    bf16x8 va[4], vb[4], wf0, wf1;
    {
        const bf16_t* Vt_ = Vh + (size_t)t0 * 4096;
#pragma unroll
        for (int db = 0; db < 4; db++) {
            const bf16_t* vp = Vt_ + db * 1024 + lane * 16;
            va[db] = *(const bf16x8*)(vp);
            vb[db] = *(const bf16x8*)(vp + 8);
        }
        const bf16_t* wp = Wh + (size_t)t0 * 64 + kg * 16;
        wf0 = *(const bf16x8*)(wp);
        wf1 = *(const bf16x8*)(wp + 8);
    }
    stageK(t0 * 64, 0);
    __syncthreads();

    for (int tt = 0; tt < NTH_; ++tt) {
        const int t   = t0 + tt;
        const int cur = tt & 1;

        // ---- issue NEXT tile's V'/w into fresh registers and K into LDS
        bf16x8 nva[4], nvb[4], nwf0, nwf1;
        if (tt + 1 < NTH_) {
            const bf16_t* Vn = Vh + (size_t)(t + 1) * 4096;
#pragma unroll
            for (int db = 0; db < 4; db++) {
                const bf16_t* vp = Vn + db * 1024 + lane * 16;
                nva[db] = *(const bf16x8*)(vp);
                nvb[db] = *(const bf16x8*)(vp + 8);
            }
            const bf16_t* wp = Wh + (size_t)(t + 1) * 64 + kg * 16;
            nwf0 = *(const bf16x8*)(wp);
            nwf1 = *(const bf16x8*)(wp + 8);
            stageK((t + 1) * 64, cur ^ 1);
        }

        const char* KB = ShBuf + (half * 2 + cur) * 8192;

        // ---- K fragments (A-operand: K[k=nb*16+lq][hd=kg*8+e]), shared by s
        bf16x8 kf0[4], kf1[4];
#pragma unroll
        for (int nb = 0; nb < 4; nb++) {
            const char* kr = KB + (nb * 16 + lq) * 128;
            kf0[nb] = *(const bf16x8*)(kr + ((kg * 16) ^ rdsw));
            kf1[nb] = *(const bf16x8*)(kr + ((64 + kg * 16) ^ rdsw));
        }

#pragma unroll
        for (int s = 0; s < 2; s++) {
            // ---- scores transposed, C-in = 0: NO vmem dependency
            f32x4 sc[4];
#pragma unroll
            for (int nb = 0; nb < 4; nb++) {
                f32x4 tacc = fzero;
                tacc = mfma16x16x32(kf0[nb], qf0[s], tacc);
                tacc = mfma16x16x32(kf1[nb], qf1[s], tacc);
                sc[nb] = tacc;
            }

            // ---- P^T = exp2(sc) in-lane (bare v_exp_f32); permuted-k A frags
            bf16x8 pa0, pa1;
#pragma unroll
            for (int nb = 0; nb < 4; nb++)
#pragma unroll
                for (int j = 0; j < 4; j++) {
                    float p = EXP2F(sc[nb][j]);
                    const int e = (nb & 1) * 4 + j;
                    if (nb < 2) pa0[e] = (bf16_t)p; else pa1[e] = (bf16_t)p;
                }

            // ---- O += P V' (operands prefetched last tile); denom += P*w
#pragma unroll
            for (int db = 0; db < 4; db++) {
                of[s][db] = mfma16x16x32(pa0, va[db], of[s][db]);
                of[s][db] = mfma16x16x32(pa1, vb[db], of[s][db]);
            }
            of_l[s] = mfma16x16x32(pa0, wf0, of_l[s]);
            of_l[s] = mfma16x16x32(pa1, wf1, of_l[s]);
        }

        // one sync per iter: publishes stageK(t+1) (vmcnt drain, which also
        // retires nva/nvb/nwf) AND guards K buffer reuse.
        __syncthreads();

        // ---- rotate prefetched registers
        if (tt + 1 < NTH_) {
#pragma unroll
            for (int db = 0; db < 4; db++) { va[db] = nva[db]; vb[db] = nvb[db]; }
            wf0 = nwf0; wf1 = nwf1;
        }
    }

    // ---- combine halves: exact fp32 sum. K region is dead -> of-exchange.
    // Layout [k][thr256]: addr = k*1024B + thr*4B -> bank = thr%32 (2-way max).
    const int thr = wq * 64 + lane;
    if (half == 1) {
#pragma unroll
        for (int s = 0; s < 2; s++)
#pragma unroll
            for (int db = 0; db < 4; db++)
#pragma unroll
                for (int j = 0; j < 4; j++)
                    exf[(s * 16 + db * 4 + j) * 256 + thr] = of[s][db][j];
        if (lq == 0) {
#pragma unroll
            for (int s = 0; s < 2; s++)
#pragma unroll
                for (int j = 0; j < 4; j++)
                    exl[((wq * 4 + kg) * 2 + s) * 4 + j] = of_l[s][j];
        }
    }
    __syncthreads();
    if (half == 0) {
#pragma unroll
        for (int s = 0; s < 2; s++) {
#pragma unroll
            for (int db = 0; db < 4; db++)
#pragma unroll
                for (int j = 0; j < 4; j++)
                    of[s][db][j] += exf[(s * 16 + db * 4 + j) * 256 + thr];
#pragma unroll
            for (int j = 0; j < 4; j++)
                of_l[s][j] += exl[((wq * 4 + kg) * 2 + s) * 4 + j];
        }

        // ---- finalize: of_l[s][j] = sum_k P*w at q=kg*4+j (replicated on lq)
#pragma unroll
        for (int s = 0; s < 2; s++) {
            float inv[4];
#pragma unroll
            for (int j = 0; j < 4; j++) inv[j] = 1.0f / of_l[s][j];
#pragma unroll
            for (int db = 0; db < 4; db++) {
                const int d = h * HD_ + db * 16 + lq;
#pragma unroll
                for (int j = 0; j < 4; j++) {
                    const int row = qbase + s * 16 + kg * 4 + j;
                    out[((size_t)b * S_ + row) * D_ + d] = of[s][db][j] * inv[j];
                }
            }
        }
    }
}

// ---------------------------------------------------------------- launch
extern "C" void kernel_launch(void* const* d_in, const int* in_sizes, int n_in,
                              void* d_out, int out_size, void* d_ws, size_t ws_size,
                              hipStream_t stream) {
    const float* hs   = (const float*)d_in[0];
    const float* mask = (const float*)d_in[1];
    const float* Wq   = (const float*)d_in[2];
    const float* bq   = (const float*)d_in[3];
    const float* Wk   = (const float*)d_in[4];
    const float* bk   = (const float*)d_in[5];
    const float* Wv   = (const float*)d_in[6];
    const float* bv   = (const float*)d_in[7];
    float* out = (float*)d_out;

    char* ws = (char*)d_ws;
    bf16_t* Xb  = (bf16_t*)(ws);                    //  8,388,608 B  [4096][1024]
    bf16_t* Wb3 = (bf16_t*)(ws + 8388608);          //  6,291,456 B  3x[1024][1024]
    bf16_t* Qb  = (bf16_t*)(ws + 14680064);         //  8,388,608 B  [B][H][S][HD]
    bf16_t* Kb  = (bf16_t*)(ws + 23068672);         //  8,388,608 B  [B][H][S][HD]
    bf16_t* Vfr = (bf16_t*)(ws + 31457280);         //  8,388,608 B  B-frag order
    float*  wfp = (float*)(ws + 39845888);          //     16,384 B  w = e^mask
    bf16_t* wfb = (bf16_t*)(ws + 39862272);         //      8,192 B  w frag table

    cvt_all<<<7172, 256, 0, stream>>>(hs, Wq, Wk, Wv, mask, Xb, Wb3, wfp, wfb);

    dim3 ggrid(D_ / 128, M_ / 128, 3);              // (8, 32, 3)
    gemm_qkv<<<ggrid, 256, 0, stream>>>(Xb, Wb3, bq, bk, bv, wfp, Qb, Kb, Vfr);

    attn_fwd<<<512, 512, 0, stream>>>(Qb, Kb, Vfr, wfb, out);
}

// Round 25
// 92.726 us; speedup vs baseline: 1.3034x; 1.3034x over previous
//
#include <hip/hip_runtime.h>
#include <hip/hip_bf16.h>
#include <math.h>

// MultiHeadAttention: B=2, S=2048, D=1024, H=16, HD=64
// Pipeline: fused cvt (+mask->w tables) | QKV GEMM (MFMA bf16, 2-phase dbuf) |
// flash attn.
// Attn (r23 body + kv-split x2): 512 blocks x 512 thr (8 waves). Waves 0-3
// sweep kv[0,1024), waves 4-7 kv[1024,2048); each wave owns 32 q-rows
// (2 subtiles). Swapped-QK, P^T in registers. Per-half K dbuf via
// global_load_lds (one __syncthreads/iter). V'/w register-prefetched one tile
// ahead (r23). QK C-in = 0. Denominator via w-fragment MFMA. Shift-free exp2
// softmax -> kv combine is a PURE fp32 SUM (exact, deterministic).
// r25 fix: launch_bounds(512,2) NOT (512,4) -- r24's 128-VGPR cap made the
// allocator squeeze to 64 VGPR and spill ~90MB scratch (the r3 failure mode).
// Occupancy target (4 waves/SIMD) comes from grid 512 x 8 waves regardless.

typedef __bf16 bf16_t;
typedef __attribute__((ext_vector_type(8))) __bf16 bf16x8;
typedef __attribute__((ext_vector_type(4))) __bf16 bf16x4;
typedef __attribute__((ext_vector_type(4))) float f32x4;

#define B_  2
#define S_  2048
#define D_  1024
#define H_  16
#define HD_ 64
#define M_  (B_ * S_)   // 4096
#define K_  D_          // 1024
#define NT_ (S_ / 64)   // 32 kv tiles
#define NTH_ (NT_ / 2)  // 16 tiles per half
#define LOG2E 1.44269504f
#define CS_Q (0.125f * LOG2E)   // folded into Q at GEMM epilogue

#if __has_builtin(__builtin_amdgcn_exp2f)
#define EXP2F(x) __builtin_amdgcn_exp2f(x)
#else
#define EXP2F(x) exp2f(x)
#endif

__device__ __forceinline__ f32x4 mfma16x16x32(bf16x8 a, bf16x8 b, f32x4 c) {
    return __builtin_amdgcn_mfma_f32_16x16x32_bf16(a, b, c, 0, 0, 0);
}

__device__ __forceinline__ void gload_lds16(const bf16_t* g, bf16_t* l) {
    __builtin_amdgcn_global_load_lds(
        (const __attribute__((address_space(1))) void*)g,
        (__attribute__((address_space(3))) void*)l,
        16, 0, 0);
}

// ---------------------------------------------------------------- conversion
// Segments: X (1,048,576 f4) | Wq | Wk | Wv (262,144 f4 each) | mask (1024 f4).
// Mask -> w = e^mask: f32 table wfp[B][S] (folded into V at GEMM epilogue)
// and bf16 B-fragment table wfb[B][32 t][4 kg][16 e] (denominator MFMA).
__global__ void cvt_all(const float* __restrict__ hs, const float* __restrict__ wq,
                        const float* __restrict__ wk, const float* __restrict__ wv,
                        const float* __restrict__ mask,
                        bf16_t* __restrict__ Xb, bf16_t* __restrict__ Wb3,
                        float* __restrict__ wfp, bf16_t* __restrict__ wfb) {
    const int i = blockIdx.x * blockDim.x + threadIdx.x;
    if (i >= 1835008) {                     // mask segment (block-aligned tail)
        const int off = i - 1835008;
        if (off < 1024) {
            float4 v = ((const float4*)mask)[off];
            float4 w4;
            w4.x = exp2f(v.x * LOG2E); w4.y = exp2f(v.y * LOG2E);
            w4.z = exp2f(v.z * LOG2E); w4.w = exp2f(v.w * LOG2E);
            ((float4*)wfp)[off] = w4;
            // bf16 fragment table: k = t*64 + nb*16 + kg*4 + j, e = nb*4 + j
            const int k4 = off * 4;
            const int bb = k4 >> 11, k = k4 & 2047;
            const int t  = k >> 6,  kt = k & 63;
            const int nb = kt >> 4, kgf = (kt >> 2) & 3;   // j = 0..3
            bf16x4 wb4;
            wb4[0] = (bf16_t)w4.x; wb4[1] = (bf16_t)w4.y;
            wb4[2] = (bf16_t)w4.z; wb4[3] = (bf16_t)w4.w;
            *(bf16x4*)&wfb[(((size_t)bb * 32 + t) * 4 + kgf) * 16 + nb * 4] = wb4;
        }
        return;
    }
    const float* src; bf16_t* dst; int off;
    if (i < 1048576)      { src = hs; dst = Xb;            off = i; }
    else if (i < 1310720) { src = wq; dst = Wb3;           off = i - 1048576; }
    else if (i < 1572864) { src = wk; dst = Wb3 + 1048576; off = i - 1310720; }
    else                  { src = wv; dst = Wb3 + 2097152; off = i - 1572864; }
    float4 v = ((const float4*)src)[off];
    bf16x4 o;
    o[0] = (bf16_t)v.x; o[1] = (bf16_t)v.y;
    o[2] = (bf16_t)v.z; o[3] = (bf16_t)v.w;
    ((bf16x4*)dst)[off] = o;
}

// ---------------------------------------------------------------- QKV GEMM
// z=0 -> Q [B][H][S][HD], PRE-SCALED by CS_Q (0.125*log2e)
// z=1 -> K [B][H][S][HD]
// z=2 -> V' in MFMA-B-fragment order, W-FOLDED: V'[k][d] = (V[k][d])*w[b][k].
//        Vfrag[bh][t][db][lane=kg*16+lq][e=nb*4+j], k = t*64+nb*16+kg*4+j,
//        d = db*16+lq.
// 2-phase LDS double-buffer: stage(k+1) issued before compute(k), one barrier.
__global__ __launch_bounds__(256, 2)
void gemm_qkv(const bf16_t* __restrict__ Xb, const bf16_t* __restrict__ Wb3,
              const float* __restrict__ bq, const float* __restrict__ bk,
              const float* __restrict__ bv,
              const float* __restrict__ wfp,
              bf16_t* __restrict__ Qo, bf16_t* __restrict__ Ko,
              bf16_t* __restrict__ Vf) {
    __shared__ bf16_t smem[2][8192];        // dbuf: A 128x32 | B 128x32 per buf
    const int z = blockIdx.z;
    const bf16_t* Wb = Wb3 + (size_t)z * (D_ * K_);
    const float* bias = (z == 0) ? bq : (z == 1) ? bk : bv;

    const int tid  = threadIdx.x;
    const int lane = tid & 63;
    const int w    = tid >> 6;
    const int wr   = w >> 1, wc = w & 1;
    const int m0   = blockIdx.y * 128;
    const int n0   = blockIdx.x * 128;

    f32x4 acc[4][4];
    const f32x4 fzero = {0.f, 0.f, 0.f, 0.f};
#pragma unroll
    for (int i = 0; i < 4; i++)
#pragma unroll
        for (int j = 0; j < 4; j++) acc[i][j] = fzero;

    const int koff = (lane >> 4) * 8;

    auto stage = [&](int k0, int buf) {
#pragma unroll
        for (int i = 0; i < 4; i++) {
            const int chunk  = w * 4 + i;
            const int byteoff = chunk * 1024 + lane * 16;
            bf16_t* ldst = &smem[buf][chunk * 512];     // wave-uniform base
            const bf16_t* gsrc;
            if (byteoff < 8192) {                        // A region
                int row = byteoff >> 6;
                int col = (byteoff & 63) >> 1;
                gsrc = Xb + (size_t)(m0 + row) * K_ + k0 + col;
            } else {                                     // B region
                int bo  = byteoff - 8192;
                int row = bo >> 6;
                int col = (bo & 63) >> 1;
                gsrc = Wb + (size_t)(n0 + row) * K_ + k0 + col;
            }
            gload_lds16(gsrc, ldst);
        }
    };

    stage(0, 0);
    __syncthreads();

    for (int kk = 0; kk < K_ / 32; ++kk) {
        const int cur = kk & 1;
        if (kk + 1 < K_ / 32) stage((kk + 1) * 32, cur ^ 1);  // overlaps below

        bf16x8 af[4], bfr[4];
#pragma unroll
        for (int m = 0; m < 4; m++) {
            int row = wr * 64 + m * 16 + (lane & 15);
            af[m] = *(const bf16x8*)&smem[cur][row * 32 + koff];
        }
#pragma unroll
        for (int n = 0; n < 4; n++) {
            int row = wc * 64 + n * 16 + (lane & 15);
            bfr[n] = *(const bf16x8*)&smem[cur][4096 + row * 32 + koff];
        }
#pragma unroll
        for (int m = 0; m < 4; m++)
#pragma unroll
            for (int n = 0; n < 4; n++)
                acc[m][n] = mfma16x16x32(af[m], bfr[n], acc[m][n]);

        // one barrier/iter: publishes stage(kk+1) AND guards buf reuse
        __syncthreads();
    }

#pragma unroll
    for (int m = 0; m < 4; m++) {
        const int gm    = m0 + wr * 64 + m * 16 + ((lane >> 4) << 2);
        const int bidx  = gm >> 11;
        const int sbase = gm & 2047;                    // multiple of 4
#pragma unroll
        for (int n = 0; n < 4; n++) {
            const int gn = n0 + wc * 64 + n * 16 + (lane & 15);
            const int h  = gn >> 6, hd = gn & 63;
            const float bias_v = bias[gn];
            const size_t bh = (size_t)bidx * H_ + h;
            if (z == 2) {
                // fragment-order, w-folded V write: one 8B store
                const int t   = sbase >> 6, k0i = sbase & 63;
                const int nb  = k0i >> 4, kgf = (k0i >> 2) & 3;
                const int db  = hd >> 4,  lqf = hd & 15;
                const float4 w4 = *(const float4*)&wfp[bidx * S_ + sbase];
                bf16x4 pack;
                pack[0] = (bf16_t)((acc[m][n][0] + bias_v) * w4.x);
                pack[1] = (bf16_t)((acc[m][n][1] + bias_v) * w4.y);
                pack[2] = (bf16_t)((acc[m][n][2] + bias_v) * w4.z);
                pack[3] = (bf16_t)((acc[m][n][3] + bias_v) * w4.w);
                bf16_t* dst = Vf + ((bh * 32 + t) * 4 + db) * 1024 +
                    (kgf * 16 + lqf) * 16 + nb * 4;
                *(bf16x4*)dst = pack;
            } else if (z == 0) {
#pragma unroll
                for (int j = 0; j < 4; j++) {
                    float y = (acc[m][n][j] + bias_v) * CS_Q;
                    Qo[(bh * S_ + sbase + j) * HD_ + hd] = (bf16_t)y;
                }
            } else {
#pragma unroll
                for (int j = 0; j < 4; j++) {
                    float y = acc[m][n][j] + bias_v;
                    Ko[(bh * S_ + sbase + j) * HD_ + hd] = (bf16_t)y;
                }
            }
        }
    }
}

// ---------------------------------------------------------------- attention
// Grid 512 (16 qtiles x 32 heads), XCD-aware. 8 waves: wq = w&3 (q-subtile),
// half = w>>2 (kv half). LDS 33.25K: 4 x K 8K (2 per half) + 512B of_l corner;
// after the loop the K region is reused as the [32][256] of-exchange.
__global__ __launch_bounds__(512, 2)
void attn_fwd(const bf16_t* __restrict__ Qb, const bf16_t* __restrict__ Kb,
              const bf16_t* __restrict__ Vf, const bf16_t* __restrict__ Wfb,
              float* __restrict__ out) {
    const int flat = blockIdx.x;
    const int xcd  = flat & 7;
    const int idx  = flat >> 3;            // 0..63
    const int bh   = xcd * 4 + (idx >> 4); // 0..31
    const int qt   = idx & 15;             // 0..15 (128-row tiles)
    const int b    = bh >> 4;
    const int h    = bh & 15;

    const int tid  = threadIdx.x, lane = tid & 63, w = tid >> 6;
    const int wq   = w & 3;
    const int half = w >> 2;

    const bf16_t* Qh = Qb + (size_t)bh * S_ * HD_;
    const bf16_t* Kh = Kb + (size_t)bh * S_ * HD_;
    const bf16_t* Vh = Vf + (size_t)bh * 32 * 4096;   // [t][db][lane][16]
    const bf16_t* Wh = Wfb + (size_t)b * 32 * 64;     // [t][kg][16]

    __shared__ char ShBuf[33280];          // 4 x K 8K | union of-exch; +512B l
    float* exf = (float*)ShBuf;            // [32][256] after loop
    float* exl = (float*)(ShBuf + 32768);  // [128] of_l corner

    const int lq   = lane & 15;
    const int kg   = lane >> 4;            // 0..3
    const int koff = kg * 8;
    const int rsub = lane >> 3;            // staging: row-in-chunk 0..7
    const int csl8 = (lane & 7) * 8;       // staging: 16B slot -> elements

    // per-half K stage (8 KB by this half's 4 waves, 2 chunks/wave)
    auto stageK = [&](int kv0, int buf) {
        bf16_t* base = (bf16_t*)(ShBuf + (half * 2 + buf) * 8192);
#pragma unroll
        for (int i = 0; i < 2; i++) {
            const int c = wq * 2 + i;                   // 0..7, wave-uniform
            bf16_t* ldst = base + c * 512;              // 1 KB chunks
            const int cel = csl8 ^ (rsub * 8);          // pre-swizzled source col
            const bf16_t* gsrc = Kh + (size_t)(kv0 + c * 8 + rsub) * HD_ + cel;
            gload_lds16(gsrc, ldst);
        }
    };

    // ---- Q fragments: 2 subtiles of 16 rows (32 rows/wave, block tile 128)
    const int qbase = qt * 128 + wq * 32;
    bf16x8 qf0[2], qf1[2];
#pragma unroll
    for (int s = 0; s < 2; s++) {
        const bf16_t* qr = Qh + (size_t)(qbase + s * 16 + lq) * HD_;
        qf0[s] = *(const bf16x8*)(qr + koff);
        qf1[s] = *(const bf16x8*)(qr + 32 + koff);
    }

    const f32x4 fzero = {0.f, 0.f, 0.f, 0.f};
    f32x4 of[2][4];
    f32x4 of_l[2];                          // denominator accumulators
#pragma unroll
    for (int s = 0; s < 2; s++) {
        of_l[s] = fzero;
#pragma unroll
        for (int i = 0; i < 4; i++) of[s][i] = fzero;
    }

    const int rdsw = (lq & 7) << 4;        // K read swizzle: (row&7)<<4 bytes
    const int t0 = half * NTH_;

    // ---- prologue: V(t0)/w(t0) into registers; K(t0) into LDS
    bf16x8 va[4], vb[4], wf0, wf1;
    {
        const bf16_t* Vt_ = Vh + (size_t)t0 * 4096;
#pragma unroll
        for (int db = 0; db < 4; db++) {
            const bf16_t* vp = Vt_ + db * 1024 + lane * 16;
            va[db] = *(const bf16x8*)(vp);
            vb[db] = *(const bf16x8*)(vp + 8);
        }
        const bf16_t* wp = Wh + (size_t)t0 * 64 + kg * 16;
        wf0 = *(const bf16x8*)(wp);
        wf1 = *(const bf16x8*)(wp + 8);
    }
    stageK(t0 * 64, 0);
    __syncthreads();

    for (int tt = 0; tt < NTH_; ++tt) {
        const int t   = t0 + tt;
        const int cur = tt & 1;

        // ---- issue NEXT tile's V'/w into fresh registers and K into LDS
        bf16x8 nva[4], nvb[4], nwf0, nwf1;
        if (tt + 1 < NTH_) {
            const bf16_t* Vn = Vh + (size_t)(t + 1) * 4096;
#pragma unroll
            for (int db = 0; db < 4; db++) {
                const bf16_t* vp = Vn + db * 1024 + lane * 16;
                nva[db] = *(const bf16x8*)(vp);
                nvb[db] = *(const bf16x8*)(vp + 8);
            }
            const bf16_t* wp = Wh + (size_t)(t + 1) * 64 + kg * 16;
            nwf0 = *(const bf16x8*)(wp);
            nwf1 = *(const bf16x8*)(wp + 8);
            stageK((t + 1) * 64, cur ^ 1);
        }

        const char* KB = ShBuf + (half * 2 + cur) * 8192;

        // ---- K fragments (A-operand: K[k=nb*16+lq][hd=kg*8+e]), shared by s
        bf16x8 kf0[4], kf1[4];
#pragma unroll
        for (int nb = 0; nb < 4; nb++) {
            const char* kr = KB + (nb * 16 + lq) * 128;
            kf0[nb] = *(const bf16x8*)(kr + ((kg * 16) ^ rdsw));
            kf1[nb] = *(const bf16x8*)(kr + ((64 + kg * 16) ^ rdsw));
        }

#pragma unroll
        for (int s = 0; s < 2; s++) {
            // ---- scores transposed, C-in = 0: NO vmem dependency
            f32x4 sc[4];
#pragma unroll
            for (int nb = 0; nb < 4; nb++) {
                f32x4 tacc = fzero;
                tacc = mfma16x16x32(kf0[nb], qf0[s], tacc);
                tacc = mfma16x16x32(kf1[nb], qf1[s], tacc);
                sc[nb] = tacc;
            }

            // ---- P^T = exp2(sc) in-lane (bare v_exp_f32); permuted-k A frags
            bf16x8 pa0, pa1;
#pragma unroll
            for (int nb = 0; nb < 4; nb++)
#pragma unroll
                for (int j = 0; j < 4; j++) {
                    float p = EXP2F(sc[nb][j]);
                    const int e = (nb & 1) * 4 + j;
                    if (nb < 2) pa0[e] = (bf16_t)p; else pa1[e] = (bf16_t)p;
                }

            // ---- O += P V' (operands prefetched last tile); denom += P*w
#pragma unroll
            for (int db = 0; db < 4; db++) {
                of[s][db] = mfma16x16x32(pa0, va[db], of[s][db]);
                of[s][db] = mfma16x16x32(pa1, vb[db], of[s][db]);
            }
            of_l[s] = mfma16x16x32(pa0, wf0, of_l[s]);
            of_l[s] = mfma16x16x32(pa1, wf1, of_l[s]);
        }

        // one sync per iter: publishes stageK(t+1) (vmcnt drain, which also
        // retires nva/nvb/nwf) AND guards K buffer reuse.
        __syncthreads();

        // ---- rotate prefetched registers
        if (tt + 1 < NTH_) {
#pragma unroll
            for (int db = 0; db < 4; db++) { va[db] = nva[db]; vb[db] = nvb[db]; }
            wf0 = nwf0; wf1 = nwf1;
        }
    }

    // ---- combine halves: exact fp32 sum. K region is dead -> of-exchange.
    // Layout [k][thr256]: addr = k*1024B + thr*4B -> bank = thr%32 (2-way max).
    const int thr = wq * 64 + lane;
    if (half == 1) {
#pragma unroll
        for (int s = 0; s < 2; s++)
#pragma unroll
            for (int db = 0; db < 4; db++)
#pragma unroll
                for (int j = 0; j < 4; j++)
                    exf[(s * 16 + db * 4 + j) * 256 + thr] = of[s][db][j];
        if (lq == 0) {
#pragma unroll
            for (int s = 0; s < 2; s++)
#pragma unroll
                for (int j = 0; j < 4; j++)
                    exl[((wq * 4 + kg) * 2 + s) * 4 + j] = of_l[s][j];
        }
    }
    __syncthreads();
    if (half == 0) {
#pragma unroll
        for (int s = 0; s < 2; s++) {
#pragma unroll
            for (int db = 0; db < 4; db++)
#pragma unroll
                for (int j = 0; j < 4; j++)
                    of[s][db][j] += exf[(s * 16 + db * 4 + j) * 256 + thr];
#pragma unroll
            for (int j = 0; j < 4; j++)
                of_l[s][j] += exl[((wq * 4 + kg) * 2 + s) * 4 + j];
        }

        // ---- finalize: of_l[s][j] = sum_k P*w at q=kg*4+j (replicated on lq)
#pragma unroll
        for (int s = 0; s < 2; s++) {
            float inv[4];
#pragma unroll
            for (int j = 0; j < 4; j++) inv[j] = 1.0f / of_l[s][j];
#pragma unroll
            for (int db = 0; db < 4; db++) {
                const int d = h * HD_ + db * 16 + lq;
#pragma unroll
                for (int j = 0; j < 4; j++) {
                    const int row = qbase + s * 16 + kg * 4 + j;
                    out[((size_t)b * S_ + row) * D_ + d] = of[s][db][j] * inv[j];
                }
            }
        }
    }
}

// ---------------------------------------------------------------- launch
extern "C" void kernel_launch(void* const* d_in, const int* in_sizes, int n_in,
                              void* d_out, int out_size, void* d_ws, size_t ws_size,
                              hipStream_t stream) {
    const float* hs   = (const float*)d_in[0];
    const float* mask = (const float*)d_in[1];
    const float* Wq   = (const float*)d_in[2];
    const float* bq   = (const float*)d_in[3];
    const float* Wk   = (const float*)d_in[4];
    const float* bk   = (const float*)d_in[5];
    const float* Wv   = (const float*)d_in[6];
    const float* bv   = (const float*)d_in[7];
    float* out = (float*)d_out;

    char* ws = (char*)d_ws;
    bf16_t* Xb  = (bf16_t*)(ws);                    //  8,388,608 B  [4096][1024]
    bf16_t* Wb3 = (bf16_t*)(ws + 8388608);          //  6,291,456 B  3x[1024][1024]
    bf16_t* Qb  = (bf16_t*)(ws + 14680064);         //  8,388,608 B  [B][H][S][HD]
    bf16_t* Kb  = (bf16_t*)(ws + 23068672);         //  8,388,608 B  [B][H][S][HD]
    bf16_t* Vfr = (bf16_t*)(ws + 31457280);         //  8,388,608 B  B-frag order
    float*  wfp = (float*)(ws + 39845888);          //     16,384 B  w = e^mask
    bf16_t* wfb = (bf16_t*)(ws + 39862272);         //      8,192 B  w frag table

    cvt_all<<<7172, 256, 0, stream>>>(hs, Wq, Wk, Wv, mask, Xb, Wb3, wfp, wfb);

    dim3 ggrid(D_ / 128, M_ / 128, 3);              // (8, 32, 3)
    gemm_qkv<<<ggrid, 256, 0, stream>>>(Xb, Wb3, bq, bk, bv, wfp, Qb, Kb, Vfr);

    attn_fwd<<<512, 512, 0, stream>>>(Qb, Kb, Vfr, wfb, out);
}

// Round 26
// 87.747 us; speedup vs baseline: 1.3774x; 1.0567x over previous
//
#include <hip/hip_runtime.h>
#include <hip/hip_bf16.h>
#include <math.h>

// MultiHeadAttention: B=2, S=2048, D=1024, H=16, HD=64
// Pipeline: fused cvt (+mask->w tables) | QKV GEMM (MFMA bf16, 2-phase dbuf) |
// flash attn (r23 structure -- best measured: 49.3us).
// Attn: 512 blocks (128-row Q tiles), 4 waves x 32 rows (2 subtiles).
// Swapped-QK, P^T in registers. K staged via global_load_lds (2-phase dbuf,
// one __syncthreads/iter; LDS 16K). V'/w register-prefetched one tile ahead.
// QK C-in = 0 (no vmem dep). Denominator via w-fragment MFMA. Bare v_exp_f32.
// r26: GEMM launch_bounds (256,2)->(256,4): grid is 768 blocks (3/CU) but the
// old bound capped residency at 2 blocks/CU; VGPR 56 fits the 128 cap easily.
// r24/r25 lesson: kv-split x2 is conclusively slower (56.7 vs 49.3us) even
// without spills -- concurrency is not the attn lever; r23 stands.

typedef __bf16 bf16_t;
typedef __attribute__((ext_vector_type(8))) __bf16 bf16x8;
typedef __attribute__((ext_vector_type(4))) __bf16 bf16x4;
typedef __attribute__((ext_vector_type(4))) float f32x4;

#define B_  2
#define S_  2048
#define D_  1024
#define H_  16
#define HD_ 64
#define M_  (B_ * S_)   // 4096
#define K_  D_          // 1024
#define NT_ (S_ / 64)   // 32 kv tiles
#define LOG2E 1.44269504f
#define CS_Q (0.125f * LOG2E)   // folded into Q at GEMM epilogue

#if __has_builtin(__builtin_amdgcn_exp2f)
#define EXP2F(x) __builtin_amdgcn_exp2f(x)
#else
#define EXP2F(x) exp2f(x)
#endif

__device__ __forceinline__ f32x4 mfma16x16x32(bf16x8 a, bf16x8 b, f32x4 c) {
    return __builtin_amdgcn_mfma_f32_16x16x32_bf16(a, b, c, 0, 0, 0);
}

__device__ __forceinline__ void gload_lds16(const bf16_t* g, bf16_t* l) {
    __builtin_amdgcn_global_load_lds(
        (const __attribute__((address_space(1))) void*)g,
        (__attribute__((address_space(3))) void*)l,
        16, 0, 0);
}

// ---------------------------------------------------------------- conversion
// Segments: X (1,048,576 f4) | Wq | Wk | Wv (262,144 f4 each) | mask (1024 f4).
// Mask -> w = e^mask: f32 table wfp[B][S] (folded into V at GEMM epilogue)
// and bf16 B-fragment table wfb[B][32 t][4 kg][16 e] (denominator MFMA).
__global__ void cvt_all(const float* __restrict__ hs, const float* __restrict__ wq,
                        const float* __restrict__ wk, const float* __restrict__ wv,
                        const float* __restrict__ mask,
                        bf16_t* __restrict__ Xb, bf16_t* __restrict__ Wb3,
                        float* __restrict__ wfp, bf16_t* __restrict__ wfb) {
    const int i = blockIdx.x * blockDim.x + threadIdx.x;
    if (i >= 1835008) {                     // mask segment (block-aligned tail)
        const int off = i - 1835008;
        if (off < 1024) {
            float4 v = ((const float4*)mask)[off];
            float4 w4;
            w4.x = exp2f(v.x * LOG2E); w4.y = exp2f(v.y * LOG2E);
            w4.z = exp2f(v.z * LOG2E); w4.w = exp2f(v.w * LOG2E);
            ((float4*)wfp)[off] = w4;
            // bf16 fragment table: k = t*64 + nb*16 + kg*4 + j, e = nb*4 + j
            const int k4 = off * 4;
            const int bb = k4 >> 11, k = k4 & 2047;
            const int t  = k >> 6,  kt = k & 63;
            const int nb = kt >> 4, kgf = (kt >> 2) & 3;   // j = 0..3
            bf16x4 wb4;
            wb4[0] = (bf16_t)w4.x; wb4[1] = (bf16_t)w4.y;
            wb4[2] = (bf16_t)w4.z; wb4[3] = (bf16_t)w4.w;
            *(bf16x4*)&wfb[(((size_t)bb * 32 + t) * 4 + kgf) * 16 + nb * 4] = wb4;
        }
        return;
    }
    const float* src; bf16_t* dst; int off;
    if (i < 1048576)      { src = hs; dst = Xb;            off = i; }
    else if (i < 1310720) { src = wq; dst = Wb3;           off = i - 1048576; }
    else if (i < 1572864) { src = wk; dst = Wb3 + 1048576; off = i - 1310720; }
    else                  { src = wv; dst = Wb3 + 2097152; off = i - 1572864; }
    float4 v = ((const float4*)src)[off];
    bf16x4 o;
    o[0] = (bf16_t)v.x; o[1] = (bf16_t)v.y;
    o[2] = (bf16_t)v.z; o[3] = (bf16_t)v.w;
    ((bf16x4*)dst)[off] = o;
}

// ---------------------------------------------------------------- QKV GEMM
// z=0 -> Q [B][H][S][HD], PRE-SCALED by CS_Q (0.125*log2e)
// z=1 -> K [B][H][S][HD]
// z=2 -> V' in MFMA-B-fragment order, W-FOLDED: V'[k][d] = (V[k][d])*w[b][k].
//        Vfrag[bh][t][db][lane=kg*16+lq][e=nb*4+j], k = t*64+nb*16+kg*4+j,
//        d = db*16+lq.
// 2-phase LDS double-buffer: stage(k+1) issued before compute(k), one barrier.
// launch_bounds(256,4): grid 768 = 3 blocks/CU; old (256,2) capped at 2.
__global__ __launch_bounds__(256, 4)
void gemm_qkv(const bf16_t* __restrict__ Xb, const bf16_t* __restrict__ Wb3,
              const float* __restrict__ bq, const float* __restrict__ bk,
              const float* __restrict__ bv,
              const float* __restrict__ wfp,
              bf16_t* __restrict__ Qo, bf16_t* __restrict__ Ko,
              bf16_t* __restrict__ Vf) {
    __shared__ bf16_t smem[2][8192];        // dbuf: A 128x32 | B 128x32 per buf
    const int z = blockIdx.z;
    const bf16_t* Wb = Wb3 + (size_t)z * (D_ * K_);
    const float* bias = (z == 0) ? bq : (z == 1) ? bk : bv;

    const int tid  = threadIdx.x;
    const int lane = tid & 63;
    const int w    = tid >> 6;
    const int wr   = w >> 1, wc = w & 1;
    const int m0   = blockIdx.y * 128;
    const int n0   = blockIdx.x * 128;

    f32x4 acc[4][4];
    const f32x4 fzero = {0.f, 0.f, 0.f, 0.f};
#pragma unroll
    for (int i = 0; i < 4; i++)
#pragma unroll
        for (int j = 0; j < 4; j++) acc[i][j] = fzero;

    const int koff = (lane >> 4) * 8;

    auto stage = [&](int k0, int buf) {
#pragma unroll
        for (int i = 0; i < 4; i++) {
            const int chunk  = w * 4 + i;
            const int byteoff = chunk * 1024 + lane * 16;
            bf16_t* ldst = &smem[buf][chunk * 512];     // wave-uniform base
            const bf16_t* gsrc;
            if (byteoff < 8192) {                        // A region
                int row = byteoff >> 6;
                int col = (byteoff & 63) >> 1;
                gsrc = Xb + (size_t)(m0 + row) * K_ + k0 + col;
            } else {                                     // B region
                int bo  = byteoff - 8192;
                int row = bo >> 6;
                int col = (bo & 63) >> 1;
                gsrc = Wb + (size_t)(n0 + row) * K_ + k0 + col;
            }
            gload_lds16(gsrc, ldst);
        }
    };

    stage(0, 0);
    __syncthreads();

    for (int kk = 0; kk < K_ / 32; ++kk) {
        const int cur = kk & 1;
        if (kk + 1 < K_ / 32) stage((kk + 1) * 32, cur ^ 1);  // overlaps below

        bf16x8 af[4], bfr[4];
#pragma unroll
        for (int m = 0; m < 4; m++) {
            int row = wr * 64 + m * 16 + (lane & 15);
            af[m] = *(const bf16x8*)&smem[cur][row * 32 + koff];
        }
#pragma unroll
        for (int n = 0; n < 4; n++) {
            int row = wc * 64 + n * 16 + (lane & 15);
            bfr[n] = *(const bf16x8*)&smem[cur][4096 + row * 32 + koff];
        }
#pragma unroll
        for (int m = 0; m < 4; m++)
#pragma unroll
            for (int n = 0; n < 4; n++)
                acc[m][n] = mfma16x16x32(af[m], bfr[n], acc[m][n]);

        // one barrier/iter: publishes stage(kk+1) AND guards buf reuse
        __syncthreads();
    }

#pragma unroll
    for (int m = 0; m < 4; m++) {
        const int gm    = m0 + wr * 64 + m * 16 + ((lane >> 4) << 2);
        const int bidx  = gm >> 11;
        const int sbase = gm & 2047;                    // multiple of 4
#pragma unroll
        for (int n = 0; n < 4; n++) {
            const int gn = n0 + wc * 64 + n * 16 + (lane & 15);
            const int h  = gn >> 6, hd = gn & 63;
            const float bias_v = bias[gn];
            const size_t bh = (size_t)bidx * H_ + h;
            if (z == 2) {
                // fragment-order, w-folded V write: one 8B store
                const int t   = sbase >> 6, k0i = sbase & 63;
                const int nb  = k0i >> 4, kgf = (k0i >> 2) & 3;
                const int db  = hd >> 4,  lqf = hd & 15;
                const float4 w4 = *(const float4*)&wfp[bidx * S_ + sbase];
                bf16x4 pack;
                pack[0] = (bf16_t)((acc[m][n][0] + bias_v) * w4.x);
                pack[1] = (bf16_t)((acc[m][n][1] + bias_v) * w4.y);
                pack[2] = (bf16_t)((acc[m][n][2] + bias_v) * w4.z);
                pack[3] = (bf16_t)((acc[m][n][3] + bias_v) * w4.w);
                bf16_t* dst = Vf + ((bh * 32 + t) * 4 + db) * 1024 +
                    (kgf * 16 + lqf) * 16 + nb * 4;
                *(bf16x4*)dst = pack;
            } else if (z == 0) {
#pragma unroll
                for (int j = 0; j < 4; j++) {
                    float y = (acc[m][n][j] + bias_v) * CS_Q;
                    Qo[(bh * S_ + sbase + j) * HD_ + hd] = (bf16_t)y;
                }
            } else {
#pragma unroll
                for (int j = 0; j < 4; j++) {
                    float y = acc[m][n][j] + bias_v;
                    Ko[(bh * S_ + sbase + j) * HD_ + hd] = (bf16_t)y;
                }
            }
        }
    }
}

// ---------------------------------------------------------------- attention
// 1-D grid of 512 (16 qtiles x 32 heads), XCD-aware: xcd = flat&7 owns 4 heads.
// LDS 16K: K dbuf 2x8K. V'/w register-prefetched one tile ahead.
__global__ __launch_bounds__(256, 2)
void attn_fwd(const bf16_t* __restrict__ Qb, const bf16_t* __restrict__ Kb,
              const bf16_t* __restrict__ Vf, const bf16_t* __restrict__ Wfb,
              float* __restrict__ out) {
    const int flat = blockIdx.x;
    const int xcd  = flat & 7;
    const int idx  = flat >> 3;            // 0..63
    const int bh   = xcd * 4 + (idx >> 4); // 0..31
    const int qt   = idx & 15;             // 0..15 (128-row tiles)
    const int b    = bh >> 4;
    const int h    = bh & 15;

    const int tid  = threadIdx.x, lane = tid & 63, w = tid >> 6;

    const bf16_t* Qh = Qb + (size_t)bh * S_ * HD_;
    const bf16_t* Kh = Kb + (size_t)bh * S_ * HD_;
    const bf16_t* Vh = Vf + (size_t)bh * 32 * 4096;   // [t][db][lane][16]
    const bf16_t* Wh = Wfb + (size_t)b * 32 * 64;     // [t][kg][16]

    __shared__ char ShBuf[16384];          // 2 x K 8K

    const int lq   = lane & 15;
    const int kg   = lane >> 4;            // 0..3
    const int koff = kg * 8;
    const int rsub = lane >> 3;            // staging: row-in-chunk 0..7
    const int csl8 = (lane & 7) * 8;       // staging: 16B slot -> elements

    auto stageK = [&](int kv0, int buf) {
        bf16_t* base = (bf16_t*)(ShBuf + buf * 8192);
#pragma unroll
        for (int i = 0; i < 2; i++) {
            const int c = w * 2 + i;                    // 0..7, wave-uniform
            bf16_t* ldst = base + c * 512;              // 1 KB chunks
            const int cel = csl8 ^ (rsub * 8);          // pre-swizzled source col
            const bf16_t* gsrc = Kh + (size_t)(kv0 + c * 8 + rsub) * HD_ + cel;
            gload_lds16(gsrc, ldst);
        }
    };

    // ---- Q fragments: 2 subtiles of 16 rows (32 rows/wave, block tile 128)
    const int qbase = qt * 128 + w * 32;
    bf16x8 qf0[2], qf1[2];
#pragma unroll
    for (int s = 0; s < 2; s++) {
        const bf16_t* qr = Qh + (size_t)(qbase + s * 16 + lq) * HD_;
        qf0[s] = *(const bf16x8*)(qr + koff);
        qf1[s] = *(const bf16x8*)(qr + 32 + koff);
    }

    const f32x4 fzero = {0.f, 0.f, 0.f, 0.f};
    f32x4 of[2][4];
    f32x4 of_l[2];                          // denominator accumulators
#pragma unroll
    for (int s = 0; s < 2; s++) {
        of_l[s] = fzero;
#pragma unroll
        for (int i = 0; i < 4; i++) of[s][i] = fzero;
    }

    const int rdsw = (lq & 7) << 4;        // K read swizzle: (row&7)<<4 bytes

    // ---- prologue: V(0)/w(0) into registers; K(0) into LDS
    bf16x8 va[4], vb[4], wf0, wf1;
    {
        const bf16_t* Vt_ = Vh;
#pragma unroll
        for (int db = 0; db < 4; db++) {
            const bf16_t* vp = Vt_ + db * 1024 + lane * 16;
            va[db] = *(const bf16x8*)(vp);
            vb[db] = *(const bf16x8*)(vp + 8);
        }
        wf0 = *(const bf16x8*)(Wh + kg * 16);
        wf1 = *(const bf16x8*)(Wh + kg * 16 + 8);
    }
    stageK(0, 0);
    __syncthreads();

    for (int t = 0; t < NT_; ++t) {
        const int cur = t & 1;

        // ---- issue NEXT tile's V'/w into fresh registers (consumed next
        //      iteration; retire under this tile's barrier drain) and K
        //      prefetch into LDS[cur^1].
        bf16x8 nva[4], nvb[4], nwf0, nwf1;
        if (t + 1 < NT_) {
            const bf16_t* Vn = Vh + (size_t)(t + 1) * 4096;
#pragma unroll
            for (int db = 0; db < 4; db++) {
                const bf16_t* vp = Vn + db * 1024 + lane * 16;
                nva[db] = *(const bf16x8*)(vp);
                nvb[db] = *(const bf16x8*)(vp + 8);
            }
            const bf16_t* wp = Wh + (size_t)(t + 1) * 64 + kg * 16;
            nwf0 = *(const bf16x8*)(wp);
            nwf1 = *(const bf16x8*)(wp + 8);
            stageK((t + 1) * 64, cur ^ 1);
        }

        const char* KB = ShBuf + cur * 8192;

        // ---- K fragments (A-operand: K[k=nb*16+lq][hd=kg*8+e]), shared by s
        bf16x8 kf0[4], kf1[4];
#pragma unroll
        for (int nb = 0; nb < 4; nb++) {
            const char* kr = KB + (nb * 16 + lq) * 128;
            kf0[nb] = *(const bf16x8*)(kr + ((kg * 16) ^ rdsw));
            kf1[nb] = *(const bf16x8*)(kr + ((64 + kg * 16) ^ rdsw));
        }

#pragma unroll
        for (int s = 0; s < 2; s++) {
            // ---- scores transposed, C-in = 0: NO vmem dependency
            f32x4 sc[4];
#pragma unroll
            for (int nb = 0; nb < 4; nb++) {
                f32x4 tacc = fzero;
                tacc = mfma16x16x32(kf0[nb], qf0[s], tacc);
                tacc = mfma16x16x32(kf1[nb], qf1[s], tacc);
                sc[nb] = tacc;
            }

            // ---- P^T = exp2(sc) in-lane (bare v_exp_f32); permuted-k A frags
            bf16x8 pa0, pa1;
#pragma unroll
            for (int nb = 0; nb < 4; nb++)
#pragma unroll
                for (int j = 0; j < 4; j++) {
                    float p = EXP2F(sc[nb][j]);
                    const int e = (nb & 1) * 4 + j;
                    if (nb < 2) pa0[e] = (bf16_t)p; else pa1[e] = (bf16_t)p;
                }

            // ---- O += P V' (operands prefetched LAST tile -> no vmem wait);
            //      denominator += P * w
#pragma unroll
            for (int db = 0; db < 4; db++) {
                of[s][db] = mfma16x16x32(pa0, va[db], of[s][db]);
                of[s][db] = mfma16x16x32(pa1, vb[db], of[s][db]);
            }
            of_l[s] = mfma16x16x32(pa0, wf0, of_l[s]);
            of_l[s] = mfma16x16x32(pa1, wf1, of_l[s]);
        }

        // one sync per iter: publishes stageK(t+1) (vmcnt drain, which also
        // retires nva/nvb/nwf) AND guards K buffer reuse.
        __syncthreads();

        // ---- rotate prefetched registers (pure renames; compiler coalesces)
        if (t + 1 < NT_) {
#pragma unroll
            for (int db = 0; db < 4; db++) { va[db] = nva[db]; vb[db] = nvb[db]; }
            wf0 = nwf0; wf1 = nwf1;
        }
    }

    // ---- finalize: of_l[s][j] = sum_k P*w at q=kg*4+j, replicated over lq.
#pragma unroll
    for (int s = 0; s < 2; s++) {
        float inv[4];
#pragma unroll
        for (int j = 0; j < 4; j++) inv[j] = 1.0f / of_l[s][j];
#pragma unroll
        for (int db = 0; db < 4; db++) {
            const int d = h * HD_ + db * 16 + lq;
#pragma unroll
            for (int j = 0; j < 4; j++) {
                const int row = qbase + s * 16 + kg * 4 + j;
                out[((size_t)b * S_ + row) * D_ + d] = of[s][db][j] * inv[j];
            }
        }
    }
}

// ---------------------------------------------------------------- launch
extern "C" void kernel_launch(void* const* d_in, const int* in_sizes, int n_in,
                              void* d_out, int out_size, void* d_ws, size_t ws_size,
                              hipStream_t stream) {
    const float* hs   = (const float*)d_in[0];
    const float* mask = (const float*)d_in[1];
    const float* Wq   = (const float*)d_in[2];
    const float* bq   = (const float*)d_in[3];
    const float* Wk   = (const float*)d_in[4];
    const float* bk   = (const float*)d_in[5];
    const float* Wv   = (const float*)d_in[6];
    const float* bv   = (const float*)d_in[7];
    float* out = (float*)d_out;

    char* ws = (char*)d_ws;
    bf16_t* Xb  = (bf16_t*)(ws);                    //  8,388,608 B  [4096][1024]
    bf16_t* Wb3 = (bf16_t*)(ws + 8388608);          //  6,291,456 B  3x[1024][1024]
    bf16_t* Qb  = (bf16_t*)(ws + 14680064);         //  8,388,608 B  [B][H][S][HD]
    bf16_t* Kb  = (bf16_t*)(ws + 23068672);         //  8,388,608 B  [B][H][S][HD]
    bf16_t* Vfr = (bf16_t*)(ws + 31457280);         //  8,388,608 B  B-frag order
    float*  wfp = (float*)(ws + 39845888);          //     16,384 B  w = e^mask
    bf16_t* wfb = (bf16_t*)(ws + 39862272);         //      8,192 B  w frag table

    cvt_all<<<7172, 256, 0, stream>>>(hs, Wq, Wk, Wv, mask, Xb, Wb3, wfp, wfb);

    dim3 ggrid(D_ / 128, M_ / 128, 3);              // (8, 32, 3)
    gemm_qkv<<<ggrid, 256, 0, stream>>>(Xb, Wb3, bq, bk, bv, wfp, Qb, Kb, Vfr);

    attn_fwd<<<512, 256, 0, stream>>>(Qb, Kb, Vfr, wfb, out);
}

// Round 27
// 87.539 us; speedup vs baseline: 1.3807x; 1.0024x over previous
//
#include <hip/hip_runtime.h>
#include <hip/hip_bf16.h>
#include <math.h>

// MultiHeadAttention: B=2, S=2048, D=1024, H=16, HD=64
// Pipeline: fused cvt (+mask->w tables) | QKV GEMM (MFMA bf16, 2-phase dbuf) |
// flash attn (r23 structure, best measured 49.3us).
// Attn: 512 blocks (128-row Q tiles), 4 waves x 32 rows (2 subtiles).
// Swapped-QK, P^T in registers. K staged via global_load_lds (2-phase dbuf,
// one __syncthreads/iter; LDS 16K). V'/w register-prefetched one tile ahead.
// QK C-in = 0. Denominator via w-fragment MFMA. Bare v_exp_f32.
// r27: PHASE-BATCHED subtiles: QK(s0)+QK(s1) -> exp(s0)+exp(s1) ->
// PV(s0)+PV(s1). The two subtiles are independent; batching doubles the ILP
// at every MFMA<->trans pipe transition (previously serialized per subtile).

typedef __bf16 bf16_t;
typedef __attribute__((ext_vector_type(8))) __bf16 bf16x8;
typedef __attribute__((ext_vector_type(4))) __bf16 bf16x4;
typedef __attribute__((ext_vector_type(4))) float f32x4;

#define B_  2
#define S_  2048
#define D_  1024
#define H_  16
#define HD_ 64
#define M_  (B_ * S_)   // 4096
#define K_  D_          // 1024
#define NT_ (S_ / 64)   // 32 kv tiles
#define LOG2E 1.44269504f
#define CS_Q (0.125f * LOG2E)   // folded into Q at GEMM epilogue

#if __has_builtin(__builtin_amdgcn_exp2f)
#define EXP2F(x) __builtin_amdgcn_exp2f(x)
#else
#define EXP2F(x) exp2f(x)
#endif

__device__ __forceinline__ f32x4 mfma16x16x32(bf16x8 a, bf16x8 b, f32x4 c) {
    return __builtin_amdgcn_mfma_f32_16x16x32_bf16(a, b, c, 0, 0, 0);
}

__device__ __forceinline__ void gload_lds16(const bf16_t* g, bf16_t* l) {
    __builtin_amdgcn_global_load_lds(
        (const __attribute__((address_space(1))) void*)g,
        (__attribute__((address_space(3))) void*)l,
        16, 0, 0);
}

// ---------------------------------------------------------------- conversion
// Segments: X (1,048,576 f4) | Wq | Wk | Wv (262,144 f4 each) | mask (1024 f4).
// Mask -> w = e^mask: f32 table wfp[B][S] (folded into V at GEMM epilogue)
// and bf16 B-fragment table wfb[B][32 t][4 kg][16 e] (denominator MFMA).
__global__ void cvt_all(const float* __restrict__ hs, const float* __restrict__ wq,
                        const float* __restrict__ wk, const float* __restrict__ wv,
                        const float* __restrict__ mask,
                        bf16_t* __restrict__ Xb, bf16_t* __restrict__ Wb3,
                        float* __restrict__ wfp, bf16_t* __restrict__ wfb) {
    const int i = blockIdx.x * blockDim.x + threadIdx.x;
    if (i >= 1835008) {                     // mask segment (block-aligned tail)
        const int off = i - 1835008;
        if (off < 1024) {
            float4 v = ((const float4*)mask)[off];
            float4 w4;
            w4.x = exp2f(v.x * LOG2E); w4.y = exp2f(v.y * LOG2E);
            w4.z = exp2f(v.z * LOG2E); w4.w = exp2f(v.w * LOG2E);
            ((float4*)wfp)[off] = w4;
            // bf16 fragment table: k = t*64 + nb*16 + kg*4 + j, e = nb*4 + j
            const int k4 = off * 4;
            const int bb = k4 >> 11, k = k4 & 2047;
            const int t  = k >> 6,  kt = k & 63;
            const int nb = kt >> 4, kgf = (kt >> 2) & 3;   // j = 0..3
            bf16x4 wb4;
            wb4[0] = (bf16_t)w4.x; wb4[1] = (bf16_t)w4.y;
            wb4[2] = (bf16_t)w4.z; wb4[3] = (bf16_t)w4.w;
            *(bf16x4*)&wfb[(((size_t)bb * 32 + t) * 4 + kgf) * 16 + nb * 4] = wb4;
        }
        return;
    }
    const float* src; bf16_t* dst; int off;
    if (i < 1048576)      { src = hs; dst = Xb;            off = i; }
    else if (i < 1310720) { src = wq; dst = Wb3;           off = i - 1048576; }
    else if (i < 1572864) { src = wk; dst = Wb3 + 1048576; off = i - 1310720; }
    else                  { src = wv; dst = Wb3 + 2097152; off = i - 1572864; }
    float4 v = ((const float4*)src)[off];
    bf16x4 o;
    o[0] = (bf16_t)v.x; o[1] = (bf16_t)v.y;
    o[2] = (bf16_t)v.z; o[3] = (bf16_t)v.w;
    ((bf16x4*)dst)[off] = o;
}

// ---------------------------------------------------------------- QKV GEMM
// z=0 -> Q [B][H][S][HD], PRE-SCALED by CS_Q (0.125*log2e)
// z=1 -> K [B][H][S][HD]
// z=2 -> V' in MFMA-B-fragment order, W-FOLDED: V'[k][d] = (V[k][d])*w[b][k].
//        Vfrag[bh][t][db][lane=kg*16+lq][e=nb*4+j], k = t*64+nb*16+kg*4+j,
//        d = db*16+lq.
// 2-phase LDS double-buffer: stage(k+1) issued before compute(k), one barrier.
__global__ __launch_bounds__(256, 4)
void gemm_qkv(const bf16_t* __restrict__ Xb, const bf16_t* __restrict__ Wb3,
              const float* __restrict__ bq, const float* __restrict__ bk,
              const float* __restrict__ bv,
              const float* __restrict__ wfp,
              bf16_t* __restrict__ Qo, bf16_t* __restrict__ Ko,
              bf16_t* __restrict__ Vf) {
    __shared__ bf16_t smem[2][8192];        // dbuf: A 128x32 | B 128x32 per buf
    const int z = blockIdx.z;
    const bf16_t* Wb = Wb3 + (size_t)z * (D_ * K_);
    const float* bias = (z == 0) ? bq : (z == 1) ? bk : bv;

    const int tid  = threadIdx.x;
    const int lane = tid & 63;
    const int w    = tid >> 6;
    const int wr   = w >> 1, wc = w & 1;
    const int m0   = blockIdx.y * 128;
    const int n0   = blockIdx.x * 128;

    f32x4 acc[4][4];
    const f32x4 fzero = {0.f, 0.f, 0.f, 0.f};
#pragma unroll
    for (int i = 0; i < 4; i++)
#pragma unroll
        for (int j = 0; j < 4; j++) acc[i][j] = fzero;

    const int koff = (lane >> 4) * 8;

    auto stage = [&](int k0, int buf) {
#pragma unroll
        for (int i = 0; i < 4; i++) {
            const int chunk  = w * 4 + i;
            const int byteoff = chunk * 1024 + lane * 16;
            bf16_t* ldst = &smem[buf][chunk * 512];     // wave-uniform base
            const bf16_t* gsrc;
            if (byteoff < 8192) {                        // A region
                int row = byteoff >> 6;
                int col = (byteoff & 63) >> 1;
                gsrc = Xb + (size_t)(m0 + row) * K_ + k0 + col;
            } else {                                     // B region
                int bo  = byteoff - 8192;
                int row = bo >> 6;
                int col = (bo & 63) >> 1;
                gsrc = Wb + (size_t)(n0 + row) * K_ + k0 + col;
            }
            gload_lds16(gsrc, ldst);
        }
    };

    stage(0, 0);
    __syncthreads();

    for (int kk = 0; kk < K_ / 32; ++kk) {
        const int cur = kk & 1;
        if (kk + 1 < K_ / 32) stage((kk + 1) * 32, cur ^ 1);  // overlaps below

        bf16x8 af[4], bfr[4];
#pragma unroll
        for (int m = 0; m < 4; m++) {
            int row = wr * 64 + m * 16 + (lane & 15);
            af[m] = *(const bf16x8*)&smem[cur][row * 32 + koff];
        }
#pragma unroll
        for (int n = 0; n < 4; n++) {
            int row = wc * 64 + n * 16 + (lane & 15);
            bfr[n] = *(const bf16x8*)&smem[cur][4096 + row * 32 + koff];
        }
#pragma unroll
        for (int m = 0; m < 4; m++)
#pragma unroll
            for (int n = 0; n < 4; n++)
                acc[m][n] = mfma16x16x32(af[m], bfr[n], acc[m][n]);

        // one barrier/iter: publishes stage(kk+1) AND guards buf reuse
        __syncthreads();
    }

#pragma unroll
    for (int m = 0; m < 4; m++) {
        const int gm    = m0 + wr * 64 + m * 16 + ((lane >> 4) << 2);
        const int bidx  = gm >> 11;
        const int sbase = gm & 2047;                    // multiple of 4
#pragma unroll
        for (int n = 0; n < 4; n++) {
            const int gn = n0 + wc * 64 + n * 16 + (lane & 15);
            const int h  = gn >> 6, hd = gn & 63;
            const float bias_v = bias[gn];
            const size_t bh = (size_t)bidx * H_ + h;
            if (z == 2) {
                // fragment-order, w-folded V write: one 8B store
                const int t   = sbase >> 6, k0i = sbase & 63;
                const int nb  = k0i >> 4, kgf = (k0i >> 2) & 3;
                const int db  = hd >> 4,  lqf = hd & 15;
                const float4 w4 = *(const float4*)&wfp[bidx * S_ + sbase];
                bf16x4 pack;
                pack[0] = (bf16_t)((acc[m][n][0] + bias_v) * w4.x);
                pack[1] = (bf16_t)((acc[m][n][1] + bias_v) * w4.y);
                pack[2] = (bf16_t)((acc[m][n][2] + bias_v) * w4.z);
                pack[3] = (bf16_t)((acc[m][n][3] + bias_v) * w4.w);
                bf16_t* dst = Vf + ((bh * 32 + t) * 4 + db) * 1024 +
                    (kgf * 16 + lqf) * 16 + nb * 4;
                *(bf16x4*)dst = pack;
            } else if (z == 0) {
#pragma unroll
                for (int j = 0; j < 4; j++) {
                    float y = (acc[m][n][j] + bias_v) * CS_Q;
                    Qo[(bh * S_ + sbase + j) * HD_ + hd] = (bf16_t)y;
                }
            } else {
#pragma unroll
                for (int j = 0; j < 4; j++) {
                    float y = acc[m][n][j] + bias_v;
                    Ko[(bh * S_ + sbase + j) * HD_ + hd] = (bf16_t)y;
                }
            }
        }
    }
}

// ---------------------------------------------------------------- attention
// 1-D grid of 512 (16 qtiles x 32 heads), XCD-aware: xcd = flat&7 owns 4 heads.
// LDS 16K: K dbuf 2x8K. V'/w register-prefetched one tile ahead.
// Phase-batched: QK both subtiles -> exp both -> PV both (max pipe overlap).
__global__ __launch_bounds__(256, 2)
void attn_fwd(const bf16_t* __restrict__ Qb, const bf16_t* __restrict__ Kb,
              const bf16_t* __restrict__ Vf, const bf16_t* __restrict__ Wfb,
              float* __restrict__ out) {
    const int flat = blockIdx.x;
    const int xcd  = flat & 7;
    const int idx  = flat >> 3;            // 0..63
    const int bh   = xcd * 4 + (idx >> 4); // 0..31
    const int qt   = idx & 15;             // 0..15 (128-row tiles)
    const int b    = bh >> 4;
    const int h    = bh & 15;

    const int tid  = threadIdx.x, lane = tid & 63, w = tid >> 6;

    const bf16_t* Qh = Qb + (size_t)bh * S_ * HD_;
    const bf16_t* Kh = Kb + (size_t)bh * S_ * HD_;
    const bf16_t* Vh = Vf + (size_t)bh * 32 * 4096;   // [t][db][lane][16]
    const bf16_t* Wh = Wfb + (size_t)b * 32 * 64;     // [t][kg][16]

    __shared__ char ShBuf[16384];          // 2 x K 8K

    const int lq   = lane & 15;
    const int kg   = lane >> 4;            // 0..3
    const int koff = kg * 8;
    const int rsub = lane >> 3;            // staging: row-in-chunk 0..7
    const int csl8 = (lane & 7) * 8;       // staging: 16B slot -> elements

    auto stageK = [&](int kv0, int buf) {
        bf16_t* base = (bf16_t*)(ShBuf + buf * 8192);
#pragma unroll
        for (int i = 0; i < 2; i++) {
            const int c = w * 2 + i;                    // 0..7, wave-uniform
            bf16_t* ldst = base + c * 512;              // 1 KB chunks
            const int cel = csl8 ^ (rsub * 8);          // pre-swizzled source col
            const bf16_t* gsrc = Kh + (size_t)(kv0 + c * 8 + rsub) * HD_ + cel;
            gload_lds16(gsrc, ldst);
        }
    };

    // ---- Q fragments: 2 subtiles of 16 rows (32 rows/wave, block tile 128)
    const int qbase = qt * 128 + w * 32;
    bf16x8 qf0[2], qf1[2];
#pragma unroll
    for (int s = 0; s < 2; s++) {
        const bf16_t* qr = Qh + (size_t)(qbase + s * 16 + lq) * HD_;
        qf0[s] = *(const bf16x8*)(qr + koff);
        qf1[s] = *(const bf16x8*)(qr + 32 + koff);
    }

    const f32x4 fzero = {0.f, 0.f, 0.f, 0.f};
    f32x4 of[2][4];
    f32x4 of_l[2];                          // denominator accumulators
#pragma unroll
    for (int s = 0; s < 2; s++) {
        of_l[s] = fzero;
#pragma unroll
        for (int i = 0; i < 4; i++) of[s][i] = fzero;
    }

    const int rdsw = (lq & 7) << 4;        // K read swizzle: (row&7)<<4 bytes

    // ---- prologue: V(0)/w(0) into registers; K(0) into LDS
    bf16x8 va[4], vb[4], wf0, wf1;
    {
        const bf16_t* Vt_ = Vh;
#pragma unroll
        for (int db = 0; db < 4; db++) {
            const bf16_t* vp = Vt_ + db * 1024 + lane * 16;
            va[db] = *(const bf16x8*)(vp);
            vb[db] = *(const bf16x8*)(vp + 8);
        }
        wf0 = *(const bf16x8*)(Wh + kg * 16);
        wf1 = *(const bf16x8*)(Wh + kg * 16 + 8);
    }
    stageK(0, 0);
    __syncthreads();

    for (int t = 0; t < NT_; ++t) {
        const int cur = t & 1;

        // ---- issue NEXT tile's V'/w into fresh registers (consumed next
        //      iteration; retire under this tile's barrier drain) and K
        //      prefetch into LDS[cur^1].
        bf16x8 nva[4], nvb[4], nwf0, nwf1;
        if (t + 1 < NT_) {
            const bf16_t* Vn = Vh + (size_t)(t + 1) * 4096;
#pragma unroll
            for (int db = 0; db < 4; db++) {
                const bf16_t* vp = Vn + db * 1024 + lane * 16;
                nva[db] = *(const bf16x8*)(vp);
                nvb[db] = *(const bf16x8*)(vp + 8);
            }
            const bf16_t* wp = Wh + (size_t)(t + 1) * 64 + kg * 16;
            nwf0 = *(const bf16x8*)(wp);
            nwf1 = *(const bf16x8*)(wp + 8);
            stageK((t + 1) * 64, cur ^ 1);
        }

        const char* KB = ShBuf + cur * 8192;

        // ---- K fragments (A-operand: K[k=nb*16+lq][hd=kg*8+e]), shared by s
        bf16x8 kf0[4], kf1[4];
#pragma unroll
        for (int nb = 0; nb < 4; nb++) {
            const char* kr = KB + (nb * 16 + lq) * 128;
            kf0[nb] = *(const bf16x8*)(kr + ((kg * 16) ^ rdsw));
            kf1[nb] = *(const bf16x8*)(kr + ((64 + kg * 16) ^ rdsw));
        }

        // ---- PHASE 1: scores for BOTH subtiles (16 MFMAs back-to-back)
        f32x4 sc[2][4];
#pragma unroll
        for (int s = 0; s < 2; s++)
#pragma unroll
            for (int nb = 0; nb < 4; nb++) {
                f32x4 tacc = fzero;
                tacc = mfma16x16x32(kf0[nb], qf0[s], tacc);
                tacc = mfma16x16x32(kf1[nb], qf1[s], tacc);
                sc[s][nb] = tacc;
            }

        // ---- PHASE 2: P^T = exp2(sc) for BOTH subtiles (trans pipe;
        //      s0's exps overlap s1's QK MFMA tail)
        bf16x8 pa0[2], pa1[2];
#pragma unroll
        for (int s = 0; s < 2; s++)
#pragma unroll
            for (int nb = 0; nb < 4; nb++)
#pragma unroll
                for (int j = 0; j < 4; j++) {
                    float p = EXP2F(sc[s][nb][j]);
                    const int e = (nb & 1) * 4 + j;
                    if (nb < 2) pa0[s][e] = (bf16_t)p; else pa1[s][e] = (bf16_t)p;
                }

        // ---- PHASE 3: PV + denominator for BOTH subtiles (20 MFMAs;
        //      s0's PV overlaps s1's exp tail)
#pragma unroll
        for (int s = 0; s < 2; s++) {
#pragma unroll
            for (int db = 0; db < 4; db++) {
                of[s][db] = mfma16x16x32(pa0[s], va[db], of[s][db]);
                of[s][db] = mfma16x16x32(pa1[s], vb[db], of[s][db]);
            }
            of_l[s] = mfma16x16x32(pa0[s], wf0, of_l[s]);
            of_l[s] = mfma16x16x32(pa1[s], wf1, of_l[s]);
        }

        // one sync per iter: publishes stageK(t+1) (vmcnt drain, which also
        // retires nva/nvb/nwf) AND guards K buffer reuse.
        __syncthreads();

        // ---- rotate prefetched registers (pure renames; compiler coalesces)
        if (t + 1 < NT_) {
#pragma unroll
            for (int db = 0; db < 4; db++) { va[db] = nva[db]; vb[db] = nvb[db]; }
            wf0 = nwf0; wf1 = nwf1;
        }
    }

    // ---- finalize: of_l[s][j] = sum_k P*w at q=kg*4+j, replicated over lq.
#pragma unroll
    for (int s = 0; s < 2; s++) {
        float inv[4];
#pragma unroll
        for (int j = 0; j < 4; j++) inv[j] = 1.0f / of_l[s][j];
#pragma unroll
        for (int db = 0; db < 4; db++) {
            const int d = h * HD_ + db * 16 + lq;
#pragma unroll
            for (int j = 0; j < 4; j++) {
                const int row = qbase + s * 16 + kg * 4 + j;
                out[((size_t)b * S_ + row) * D_ + d] = of[s][db][j] * inv[j];
            }
        }
    }
}

// ---------------------------------------------------------------- launch
extern "C" void kernel_launch(void* const* d_in, const int* in_sizes, int n_in,
                              void* d_out, int out_size, void* d_ws, size_t ws_size,
                              hipStream_t stream) {
    const float* hs   = (const float*)d_in[0];
    const float* mask = (const float*)d_in[1];
    const float* Wq   = (const float*)d_in[2];
    const float* bq   = (const float*)d_in[3];
    const float* Wk   = (const float*)d_in[4];
    const float* bk   = (const float*)d_in[5];
    const float* Wv   = (const float*)d_in[6];
    const float* bv   = (const float*)d_in[7];
    float* out = (float*)d_out;

    char* ws = (char*)d_ws;
    bf16_t* Xb  = (bf16_t*)(ws);                    //  8,388,608 B  [4096][1024]
    bf16_t* Wb3 = (bf16_t*)(ws + 8388608);          //  6,291,456 B  3x[1024][1024]
    bf16_t* Qb  = (bf16_t*)(ws + 14680064);         //  8,388,608 B  [B][H][S][HD]
    bf16_t* Kb  = (bf16_t*)(ws + 23068672);         //  8,388,608 B  [B][H][S][HD]
    bf16_t* Vfr = (bf16_t*)(ws + 31457280);         //  8,388,608 B  B-frag order
    float*  wfp = (float*)(ws + 39845888);          //     16,384 B  w = e^mask
    bf16_t* wfb = (bf16_t*)(ws + 39862272);         //      8,192 B  w frag table

    cvt_all<<<7172, 256, 0, stream>>>(hs, Wq, Wk, Wv, mask, Xb, Wb3, wfp, wfb);

    dim3 ggrid(D_ / 128, M_ / 128, 3);              // (8, 32, 3)
    gemm_qkv<<<ggrid, 256, 0, stream>>>(Xb, Wb3, bq, bk, bv, wfp, Qb, Kb, Vfr);

    attn_fwd<<<512, 256, 0, stream>>>(Qb, Kb, Vfr, wfb, out);
}

// Round 28
// 86.492 us; speedup vs baseline: 1.3974x; 1.0121x over previous
//
#include <hip/hip_runtime.h>
#include <hip/hip_bf16.h>
#include <math.h>

// MultiHeadAttention: B=2, S=2048, D=1024, H=16, HD=64
// Pipeline: fused cvt (+mask->w tables) | QKV GEMM (MFMA bf16, 2-phase dbuf) |
// flash attn.
// Attn (r23 + deferred exp/PV pipeline): 512 blocks (128-row Q tiles), 4 waves
// x 32 rows (2 subtiles). Swapped-QK, P^T in registers. K staged via
// global_load_lds (2-phase dbuf, one __syncthreads/iter; LDS 16K). V'/w
// register-prefetched (3-deep rotation). QK C-in = 0. Denominator via
// w-fragment MFMA. Bare v_exp_f32.
// r28: exp+PV run ONE TILE BEHIND QK: iteration t = {issue kf(t) ds_reads;
// exp+PV(t-1) <- hides the ~120cy LDS latency of the kf reads; QK(t)->sc
// (loop-carried); prefetch V/w + stageK(t+1); barrier; rotate}. Epilogue
// finishes tile NT-1. All moved work is register-local -> no sync change.

typedef __bf16 bf16_t;
typedef __attribute__((ext_vector_type(8))) __bf16 bf16x8;
typedef __attribute__((ext_vector_type(4))) __bf16 bf16x4;
typedef __attribute__((ext_vector_type(4))) float f32x4;

#define B_  2
#define S_  2048
#define D_  1024
#define H_  16
#define HD_ 64
#define M_  (B_ * S_)   // 4096
#define K_  D_          // 1024
#define NT_ (S_ / 64)   // 32 kv tiles
#define LOG2E 1.44269504f
#define CS_Q (0.125f * LOG2E)   // folded into Q at GEMM epilogue

#if __has_builtin(__builtin_amdgcn_exp2f)
#define EXP2F(x) __builtin_amdgcn_exp2f(x)
#else
#define EXP2F(x) exp2f(x)
#endif

__device__ __forceinline__ f32x4 mfma16x16x32(bf16x8 a, bf16x8 b, f32x4 c) {
    return __builtin_amdgcn_mfma_f32_16x16x32_bf16(a, b, c, 0, 0, 0);
}

__device__ __forceinline__ void gload_lds16(const bf16_t* g, bf16_t* l) {
    __builtin_amdgcn_global_load_lds(
        (const __attribute__((address_space(1))) void*)g,
        (__attribute__((address_space(3))) void*)l,
        16, 0, 0);
}

// ---------------------------------------------------------------- conversion
// Segments: X (1,048,576 f4) | Wq | Wk | Wv (262,144 f4 each) | mask (1024 f4).
// Mask -> w = e^mask: f32 table wfp[B][S] (folded into V at GEMM epilogue)
// and bf16 B-fragment table wfb[B][32 t][4 kg][16 e] (denominator MFMA).
__global__ void cvt_all(const float* __restrict__ hs, const float* __restrict__ wq,
                        const float* __restrict__ wk, const float* __restrict__ wv,
                        const float* __restrict__ mask,
                        bf16_t* __restrict__ Xb, bf16_t* __restrict__ Wb3,
                        float* __restrict__ wfp, bf16_t* __restrict__ wfb) {
    const int i = blockIdx.x * blockDim.x + threadIdx.x;
    if (i >= 1835008) {                     // mask segment (block-aligned tail)
        const int off = i - 1835008;
        if (off < 1024) {
            float4 v = ((const float4*)mask)[off];
            float4 w4;
            w4.x = exp2f(v.x * LOG2E); w4.y = exp2f(v.y * LOG2E);
            w4.z = exp2f(v.z * LOG2E); w4.w = exp2f(v.w * LOG2E);
            ((float4*)wfp)[off] = w4;
            // bf16 fragment table: k = t*64 + nb*16 + kg*4 + j, e = nb*4 + j
            const int k4 = off * 4;
            const int bb = k4 >> 11, k = k4 & 2047;
            const int t  = k >> 6,  kt = k & 63;
            const int nb = kt >> 4, kgf = (kt >> 2) & 3;   // j = 0..3
            bf16x4 wb4;
            wb4[0] = (bf16_t)w4.x; wb4[1] = (bf16_t)w4.y;
            wb4[2] = (bf16_t)w4.z; wb4[3] = (bf16_t)w4.w;
            *(bf16x4*)&wfb[(((size_t)bb * 32 + t) * 4 + kgf) * 16 + nb * 4] = wb4;
        }
        return;
    }
    const float* src; bf16_t* dst; int off;
    if (i < 1048576)      { src = hs; dst = Xb;            off = i; }
    else if (i < 1310720) { src = wq; dst = Wb3;           off = i - 1048576; }
    else if (i < 1572864) { src = wk; dst = Wb3 + 1048576; off = i - 1310720; }
    else                  { src = wv; dst = Wb3 + 2097152; off = i - 1572864; }
    float4 v = ((const float4*)src)[off];
    bf16x4 o;
    o[0] = (bf16_t)v.x; o[1] = (bf16_t)v.y;
    o[2] = (bf16_t)v.z; o[3] = (bf16_t)v.w;
    ((bf16x4*)dst)[off] = o;
}

// ---------------------------------------------------------------- QKV GEMM
// z=0 -> Q [B][H][S][HD], PRE-SCALED by CS_Q (0.125*log2e)
// z=1 -> K [B][H][S][HD]
// z=2 -> V' in MFMA-B-fragment order, W-FOLDED: V'[k][d] = (V[k][d])*w[b][k].
//        Vfrag[bh][t][db][lane=kg*16+lq][e=nb*4+j], k = t*64+nb*16+kg*4+j,
//        d = db*16+lq.
// 2-phase LDS double-buffer: stage(k+1) issued before compute(k), one barrier.
__global__ __launch_bounds__(256, 4)
void gemm_qkv(const bf16_t* __restrict__ Xb, const bf16_t* __restrict__ Wb3,
              const float* __restrict__ bq, const float* __restrict__ bk,
              const float* __restrict__ bv,
              const float* __restrict__ wfp,
              bf16_t* __restrict__ Qo, bf16_t* __restrict__ Ko,
              bf16_t* __restrict__ Vf) {
    __shared__ bf16_t smem[2][8192];        // dbuf: A 128x32 | B 128x32 per buf
    const int z = blockIdx.z;
    const bf16_t* Wb = Wb3 + (size_t)z * (D_ * K_);
    const float* bias = (z == 0) ? bq : (z == 1) ? bk : bv;

    const int tid  = threadIdx.x;
    const int lane = tid & 63;
    const int w    = tid >> 6;
    const int wr   = w >> 1, wc = w & 1;
    const int m0   = blockIdx.y * 128;
    const int n0   = blockIdx.x * 128;

    f32x4 acc[4][4];
    const f32x4 fzero = {0.f, 0.f, 0.f, 0.f};
#pragma unroll
    for (int i = 0; i < 4; i++)
#pragma unroll
        for (int j = 0; j < 4; j++) acc[i][j] = fzero;

    const int koff = (lane >> 4) * 8;

    auto stage = [&](int k0, int buf) {
#pragma unroll
        for (int i = 0; i < 4; i++) {
            const int chunk  = w * 4 + i;
            const int byteoff = chunk * 1024 + lane * 16;
            bf16_t* ldst = &smem[buf][chunk * 512];     // wave-uniform base
            const bf16_t* gsrc;
            if (byteoff < 8192) {                        // A region
                int row = byteoff >> 6;
                int col = (byteoff & 63) >> 1;
                gsrc = Xb + (size_t)(m0 + row) * K_ + k0 + col;
            } else {                                     // B region
                int bo  = byteoff - 8192;
                int row = bo >> 6;
                int col = (bo & 63) >> 1;
                gsrc = Wb + (size_t)(n0 + row) * K_ + k0 + col;
            }
            gload_lds16(gsrc, ldst);
        }
    };

    stage(0, 0);
    __syncthreads();

    for (int kk = 0; kk < K_ / 32; ++kk) {
        const int cur = kk & 1;
        if (kk + 1 < K_ / 32) stage((kk + 1) * 32, cur ^ 1);  // overlaps below

        bf16x8 af[4], bfr[4];
#pragma unroll
        for (int m = 0; m < 4; m++) {
            int row = wr * 64 + m * 16 + (lane & 15);
            af[m] = *(const bf16x8*)&smem[cur][row * 32 + koff];
        }
#pragma unroll
        for (int n = 0; n < 4; n++) {
            int row = wc * 64 + n * 16 + (lane & 15);
            bfr[n] = *(const bf16x8*)&smem[cur][4096 + row * 32 + koff];
        }
#pragma unroll
        for (int m = 0; m < 4; m++)
#pragma unroll
            for (int n = 0; n < 4; n++)
                acc[m][n] = mfma16x16x32(af[m], bfr[n], acc[m][n]);

        // one barrier/iter: publishes stage(kk+1) AND guards buf reuse
        __syncthreads();
    }

#pragma unroll
    for (int m = 0; m < 4; m++) {
        const int gm    = m0 + wr * 64 + m * 16 + ((lane >> 4) << 2);
        const int bidx  = gm >> 11;
        const int sbase = gm & 2047;                    // multiple of 4
#pragma unroll
        for (int n = 0; n < 4; n++) {
            const int gn = n0 + wc * 64 + n * 16 + (lane & 15);
            const int h  = gn >> 6, hd = gn & 63;
            const float bias_v = bias[gn];
            const size_t bh = (size_t)bidx * H_ + h;
            if (z == 2) {
                // fragment-order, w-folded V write: one 8B store
                const int t   = sbase >> 6, k0i = sbase & 63;
                const int nb  = k0i >> 4, kgf = (k0i >> 2) & 3;
                const int db  = hd >> 4,  lqf = hd & 15;
                const float4 w4 = *(const float4*)&wfp[bidx * S_ + sbase];
                bf16x4 pack;
                pack[0] = (bf16_t)((acc[m][n][0] + bias_v) * w4.x);
                pack[1] = (bf16_t)((acc[m][n][1] + bias_v) * w4.y);
                pack[2] = (bf16_t)((acc[m][n][2] + bias_v) * w4.z);
                pack[3] = (bf16_t)((acc[m][n][3] + bias_v) * w4.w);
                bf16_t* dst = Vf + ((bh * 32 + t) * 4 + db) * 1024 +
                    (kgf * 16 + lqf) * 16 + nb * 4;
                *(bf16x4*)dst = pack;
            } else if (z == 0) {
#pragma unroll
                for (int j = 0; j < 4; j++) {
                    float y = (acc[m][n][j] + bias_v) * CS_Q;
                    Qo[(bh * S_ + sbase + j) * HD_ + hd] = (bf16_t)y;
                }
            } else {
#pragma unroll
                for (int j = 0; j < 4; j++) {
                    float y = acc[m][n][j] + bias_v;
                    Ko[(bh * S_ + sbase + j) * HD_ + hd] = (bf16_t)y;
                }
            }
        }
    }
}

// ---------------------------------------------------------------- attention
// 1-D grid of 512 (16 qtiles x 32 heads), XCD-aware: xcd = flat&7 owns 4 heads.
// LDS 16K: K dbuf 2x8K. Deferred exp/PV pipeline (one tile behind QK).
__global__ __launch_bounds__(256, 2)
void attn_fwd(const bf16_t* __restrict__ Qb, const bf16_t* __restrict__ Kb,
              const bf16_t* __restrict__ Vf, const bf16_t* __restrict__ Wfb,
              float* __restrict__ out) {
    const int flat = blockIdx.x;
    const int xcd  = flat & 7;
    const int idx  = flat >> 3;            // 0..63
    const int bh   = xcd * 4 + (idx >> 4); // 0..31
    const int qt   = idx & 15;             // 0..15 (128-row tiles)
    const int b    = bh >> 4;
    const int h    = bh & 15;

    const int tid  = threadIdx.x, lane = tid & 63, w = tid >> 6;

    const bf16_t* Qh = Qb + (size_t)bh * S_ * HD_;
    const bf16_t* Kh = Kb + (size_t)bh * S_ * HD_;
    const bf16_t* Vh = Vf + (size_t)bh * 32 * 4096;   // [t][db][lane][16]
    const bf16_t* Wh = Wfb + (size_t)b * 32 * 64;     // [t][kg][16]

    __shared__ char ShBuf[16384];          // 2 x K 8K

    const int lq   = lane & 15;
    const int kg   = lane >> 4;            // 0..3
    const int koff = kg * 8;
    const int rsub = lane >> 3;            // staging: row-in-chunk 0..7
    const int csl8 = (lane & 7) * 8;       // staging: 16B slot -> elements

    auto stageK = [&](int kv0, int buf) {
        bf16_t* base = (bf16_t*)(ShBuf + buf * 8192);
#pragma unroll
        for (int i = 0; i < 2; i++) {
            const int c = w * 2 + i;                    // 0..7, wave-uniform
            bf16_t* ldst = base + c * 512;              // 1 KB chunks
            const int cel = csl8 ^ (rsub * 8);          // pre-swizzled source col
            const bf16_t* gsrc = Kh + (size_t)(kv0 + c * 8 + rsub) * HD_ + cel;
            gload_lds16(gsrc, ldst);
        }
    };

    // ---- Q fragments: 2 subtiles of 16 rows (32 rows/wave, block tile 128)
    const int qbase = qt * 128 + w * 32;
    bf16x8 qf0[2], qf1[2];
#pragma unroll
    for (int s = 0; s < 2; s++) {
        const bf16_t* qr = Qh + (size_t)(qbase + s * 16 + lq) * HD_;
        qf0[s] = *(const bf16x8*)(qr + koff);
        qf1[s] = *(const bf16x8*)(qr + 32 + koff);
    }

    const f32x4 fzero = {0.f, 0.f, 0.f, 0.f};
    f32x4 of[2][4];
    f32x4 of_l[2];                          // denominator accumulators
#pragma unroll
    for (int s = 0; s < 2; s++) {
        of_l[s] = fzero;
#pragma unroll
        for (int i = 0; i < 4; i++) of[s][i] = fzero;
    }

    const int rdsw = (lq & 7) << 4;        // K read swizzle: (row&7)<<4 bytes

    // ---- V/w 3-deep rotation: vA = PV-use (tile t-1), vB = next, vC = load
    bf16x8 vA[4], vB[4], vC[4], wA0, wA1, wB0, wB1, wC0, wC1;
    {
        // prologue: V(0)/w(0) into vB/wB; K(0) into LDS
        const bf16_t* Vt_ = Vh;
#pragma unroll
        for (int db = 0; db < 4; db++) {
            const bf16_t* vp = Vt_ + db * 1024 + lane * 16;
            vB[db] = *(const bf16x8*)(vp);
            vC[db] = *(const bf16x8*)(vp + 8);   // temp: second half
        }
        // pack: vB holds low 8, vC high 8 -> rename into vB/vBhi scheme:
        // keep convention: per tile we need TWO bf16x8 per db (va/vb). To keep
        // the rotation simple we store them as vA/vB pairs per generation.
        wB0 = *(const bf16x8*)(Wh + kg * 16);
        wB1 = *(const bf16x8*)(Wh + kg * 16 + 8);
    }
    // Generation storage: low half in vLo?[4], high half in vHi?[4].
    bf16x8 vLoA[4], vHiA[4], vLoB[4], vHiB[4], vLoC[4], vHiC[4];
#pragma unroll
    for (int db = 0; db < 4; db++) { vLoB[db] = vB[db]; vHiB[db] = vC[db]; }
    stageK(0, 0);
    __syncthreads();

    f32x4 sc[2][4];                         // loop-carried scores (tile t-1)

    for (int t = 0; t < NT_; ++t) {
        const int cur = t & 1;
        const char* KB = ShBuf + cur * 8192;

        // ---- (1) issue K-frag ds_reads for tile t (latency hidden by (2))
        bf16x8 kf0[4], kf1[4];
#pragma unroll
        for (int nb = 0; nb < 4; nb++) {
            const char* kr = KB + (nb * 16 + lq) * 128;
            kf0[nb] = *(const bf16x8*)(kr + ((kg * 16) ^ rdsw));
            kf1[nb] = *(const bf16x8*)(kr + ((64 + kg * 16) ^ rdsw));
        }

        // ---- (2) deferred exp + PV for tile t-1 (register-only work)
        if (t > 0) {
            bf16x8 pa0[2], pa1[2];
#pragma unroll
            for (int s = 0; s < 2; s++)
#pragma unroll
                for (int nb = 0; nb < 4; nb++)
#pragma unroll
                    for (int j = 0; j < 4; j++) {
                        float p = EXP2F(sc[s][nb][j]);
                        const int e = (nb & 1) * 4 + j;
                        if (nb < 2) pa0[s][e] = (bf16_t)p;
                        else        pa1[s][e] = (bf16_t)p;
                    }
#pragma unroll
            for (int s = 0; s < 2; s++) {
#pragma unroll
                for (int db = 0; db < 4; db++) {
                    of[s][db] = mfma16x16x32(pa0[s], vLoA[db], of[s][db]);
                    of[s][db] = mfma16x16x32(pa1[s], vHiA[db], of[s][db]);
                }
                of_l[s] = mfma16x16x32(pa0[s], wA0, of_l[s]);
                of_l[s] = mfma16x16x32(pa1[s], wA1, of_l[s]);
            }
        }

        // ---- (3) QK for tile t -> loop-carried sc
#pragma unroll
        for (int s = 0; s < 2; s++)
#pragma unroll
            for (int nb = 0; nb < 4; nb++) {
                f32x4 tacc = fzero;
                tacc = mfma16x16x32(kf0[nb], qf0[s], tacc);
                tacc = mfma16x16x32(kf1[nb], qf1[s], tacc);
                sc[s][nb] = tacc;
            }

        // ---- (4) prefetch V(t+1)/w(t+1) into vC/wC; stageK(t+1)
        if (t + 1 < NT_) {
            const bf16_t* Vn = Vh + (size_t)(t + 1) * 4096;
#pragma unroll
            for (int db = 0; db < 4; db++) {
                const bf16_t* vp = Vn + db * 1024 + lane * 16;
                vLoC[db] = *(const bf16x8*)(vp);
                vHiC[db] = *(const bf16x8*)(vp + 8);
            }
            const bf16_t* wp = Wh + (size_t)(t + 1) * 64 + kg * 16;
            wC0 = *(const bf16x8*)(wp);
            wC1 = *(const bf16x8*)(wp + 8);
            stageK((t + 1) * 64, cur ^ 1);
        }

        // ---- (5) one sync per iter: publishes stageK(t+1) (vmcnt drain,
        //      which also retires vC/wC) AND guards K buffer reuse.
        __syncthreads();

        // ---- (6) rotate generations (register renames)
#pragma unroll
        for (int db = 0; db < 4; db++) {
            vLoA[db] = vLoB[db]; vHiA[db] = vHiB[db];
            vLoB[db] = vLoC[db]; vHiB[db] = vHiC[db];
        }
        wA0 = wB0; wA1 = wB1;
        wB0 = wC0; wB1 = wC1;
    }

    // ---- epilogue: exp + PV for the final tile (vA = V(NT-1), wA = w(NT-1))
    {
        bf16x8 pa0[2], pa1[2];
#pragma unroll
        for (int s = 0; s < 2; s++)
#pragma unroll
            for (int nb = 0; nb < 4; nb++)
#pragma unroll
                for (int j = 0; j < 4; j++) {
                    float p = EXP2F(sc[s][nb][j]);
                    const int e = (nb & 1) * 4 + j;
                    if (nb < 2) pa0[s][e] = (bf16_t)p;
                    else        pa1[s][e] = (bf16_t)p;
                }
#pragma unroll
        for (int s = 0; s < 2; s++) {
#pragma unroll
            for (int db = 0; db < 4; db++) {
                of[s][db] = mfma16x16x32(pa0[s], vLoA[db], of[s][db]);
                of[s][db] = mfma16x16x32(pa1[s], vHiA[db], of[s][db]);
            }
            of_l[s] = mfma16x16x32(pa0[s], wA0, of_l[s]);
            of_l[s] = mfma16x16x32(pa1[s], wA1, of_l[s]);
        }
    }

    // ---- finalize: of_l[s][j] = sum_k P*w at q=kg*4+j, replicated over lq.
#pragma unroll
    for (int s = 0; s < 2; s++) {
        float inv[4];
#pragma unroll
        for (int j = 0; j < 4; j++) inv[j] = 1.0f / of_l[s][j];
#pragma unroll
        for (int db = 0; db < 4; db++) {
            const int d = h * HD_ + db * 16 + lq;
#pragma unroll
            for (int j = 0; j < 4; j++) {
                const int row = qbase + s * 16 + kg * 4 + j;
                out[((size_t)b * S_ + row) * D_ + d] = of[s][db][j] * inv[j];
            }
        }
    }
}

// ---------------------------------------------------------------- launch
extern "C" void kernel_launch(void* const* d_in, const int* in_sizes, int n_in,
                              void* d_out, int out_size, void* d_ws, size_t ws_size,
                              hipStream_t stream) {
    const float* hs   = (const float*)d_in[0];
    const float* mask = (const float*)d_in[1];
    const float* Wq   = (const float*)d_in[2];
    const float* bq   = (const float*)d_in[3];
    const float* Wk   = (const float*)d_in[4];
    const float* bk   = (const float*)d_in[5];
    const float* Wv   = (const float*)d_in[6];
    const float* bv   = (const float*)d_in[7];
    float* out = (float*)d_out;

    char* ws = (char*)d_ws;
    bf16_t* Xb  = (bf16_t*)(ws);                    //  8,388,608 B  [4096][1024]
    bf16_t* Wb3 = (bf16_t*)(ws + 8388608);          //  6,291,456 B  3x[1024][1024]
    bf16_t* Qb  = (bf16_t*)(ws + 14680064);         //  8,388,608 B  [B][H][S][HD]
    bf16_t* Kb  = (bf16_t*)(ws + 23068672);         //  8,388,608 B  [B][H][S][HD]
    bf16_t* Vfr = (bf16_t*)(ws + 31457280);         //  8,388,608 B  B-frag order
    float*  wfp = (float*)(ws + 39845888);          //     16,384 B  w = e^mask
    bf16_t* wfb = (bf16_t*)(ws + 39862272);         //      8,192 B  w frag table

    cvt_all<<<7172, 256, 0, stream>>>(hs, Wq, Wk, Wv, mask, Xb, Wb3, wfp, wfb);

    dim3 ggrid(D_ / 128, M_ / 128, 3);              // (8, 32, 3)
    gemm_qkv<<<ggrid, 256, 0, stream>>>(Xb, Wb3, bq, bk, bv, wfp, Qb, Kb, Vfr);

    attn_fwd<<<512, 256, 0, stream>>>(Qb, Kb, Vfr, wfb, out);
}